// Round 1
// 290.768 us; speedup vs baseline: 1.0498x; 1.0498x over previous
//
#include <hip/hip_runtime.h>
#include <math.h>

#define NSEQ 1536
#define HD3  1536      // fused qkv row stride
#define RKLD 512       // rel_k row stride
#define RLEN 3071
#define NB   12

typedef __attribute__((ext_vector_type(8))) short bf16x8;
typedef __attribute__((ext_vector_type(4))) float f32x4;

__device__ __forceinline__ unsigned short f2bf(float f) {
    union { float f; unsigned u; } v; v.f = f;
    unsigned r = v.u + 0x7fffu + ((v.u >> 16) & 1u);
    return (unsigned short)(r >> 16);
}
__device__ __forceinline__ float bf2f(unsigned short s) {
    union { unsigned u; float f; } v; v.u = ((unsigned)s) << 16;
    return v.f;
}
__device__ __forceinline__ void cp16(const void* g, void* l) {
    __builtin_amdgcn_global_load_lds(
        (const __attribute__((address_space(1))) void*)g,
        (__attribute__((address_space(3))) void*)l, 16, 0, 0);
}

// LDS swizzles: keep 8-short chunks contiguous; XOR chunk id with row bits to
// break power-of-2 stride bank conflicts.
#define KSWZ(row, d) ((row) * 64 + (((((d) >> 3) ^ ((row) & 7))) << 3) + ((d) & 7))
#define PSWZ(r, j)   ((r) * 128 + (((((j) >> 3) ^ ((r) & 15))) << 3) + ((j) & 7))
#define VSTR 136     // Vt row stride in shorts (272B: 16B-aligned, non-pow2)

// ---------------------------------------------------------------------------
// fp32 -> bf16 hi-only (2-term GEMM never reads A-low)
// ---------------------------------------------------------------------------
__global__ __launch_bounds__(256) void splitf_h(
    const float* __restrict__ X, unsigned short* __restrict__ H, int n4)
{
    int i = blockIdx.x * 256 + threadIdx.x;
    if (i >= n4) return;
    float4 v = ((const float4*)X)[i];
    ushort4 hh;
    hh.x = f2bf(v.x); hh.y = f2bf(v.y); hh.z = f2bf(v.z); hh.w = f2bf(v.w);
    ((ushort4*)H)[i] = hh;
}

// ---------------------------------------------------------------------------
// Weight transpose + split (generic): W[K][N] f32 -> Th/Tl[n_off+N][ldt] bf16
// ---------------------------------------------------------------------------
__device__ __forceinline__ void wsplit_body(
    const float* __restrict__ W, unsigned short* __restrict__ Th,
    unsigned short* __restrict__ Tl, int K, int N, int n_off, int ldt, float scale,
    int bx, int by)
{
    __shared__ float tile[64][65];
    const int k0 = by * 64, n0 = bx * 64;
    const int t = threadIdx.x;
    const int rr = t >> 4, c4 = (t & 15) * 4;
#pragma unroll
    for (int p = 0; p < 4; ++p) {
        int r = p * 16 + rr;
        float4 v = *(const float4*)(W + (size_t)(k0 + r) * N + n0 + c4);
        tile[r][c4 + 0] = v.x; tile[r][c4 + 1] = v.y;
        tile[r][c4 + 2] = v.z; tile[r][c4 + 3] = v.w;
    }
    __syncthreads();
#pragma unroll
    for (int p = 0; p < 4; ++p) {
        int n = p * 16 + rr;
        float a0 = tile[c4 + 0][n] * scale;
        float a1 = tile[c4 + 1][n] * scale;
        float a2 = tile[c4 + 2][n] * scale;
        float a3 = tile[c4 + 3][n] * scale;
        ushort4 hh, ll;
        hh.x = f2bf(a0); ll.x = f2bf(a0 - bf2f(hh.x));
        hh.y = f2bf(a1); ll.y = f2bf(a1 - bf2f(hh.y));
        hh.z = f2bf(a2); ll.z = f2bf(a2 - bf2f(hh.z));
        hh.w = f2bf(a3); ll.w = f2bf(a3 - bf2f(hh.w));
        size_t o = (size_t)(n_off + n0 + n) * ldt + k0 + c4;
        *(ushort4*)(Th + o) = hh;
        *(ushort4*)(Tl + o) = ll;
    }
}

__global__ __launch_bounds__(256) void wsplit_qkv(
    const float* __restrict__ Wq, const float* __restrict__ Wk,
    const float* __restrict__ Wv, unsigned short* __restrict__ Th,
    unsigned short* __restrict__ Tl)
{
    const int z = blockIdx.z;
    const float* W = (z == 0) ? Wq : (z == 1) ? Wk : Wv;
    wsplit_body(W, Th, Tl, 1536, 512, z * 512, 1536, (z == 0) ? 0.125f : 1.f,
                blockIdx.x, blockIdx.y);
}

__global__ __launch_bounds__(256) void wsplit_t(
    const float* __restrict__ W, unsigned short* __restrict__ Th,
    unsigned short* __restrict__ Tl, int K, int N, int n_off, int ldt, float scale)
{
    wsplit_body(W, Th, Tl, K, N, n_off, ldt, scale, blockIdx.x, blockIdx.y);
}

// ---------------------------------------------------------------------------
// 2-term split-bf16 MFMA GEMM, 128x64 tile: C = Ah·(Bh+Bl)^T (+bias).
// Depth-2 prefetch pipeline (3 LDS buffers) with RAW s_barrier + counted
// vmcnt(4): the next-next stage's global_load_lds stay in flight across the
// barrier instead of being drained by the compiler's vmcnt(0). This kernel is
// latency-bound (grid 576 -> 2.25 blocks/CU; MfmaUtil 22%, HBM 16%), so the
// ~800cy/step exposed load latency is the target. 48KB LDS; XCD block swizzle.
// ---------------------------------------------------------------------------
__global__ __launch_bounds__(256) void gemm_mfma2(
    const unsigned short* __restrict__ Ah,
    const unsigned short* __restrict__ Bh, const unsigned short* __restrict__ Bl,
    const float* __restrict__ bias, float* __restrict__ C,
    int M, int N, int K)
{
    __shared__ unsigned short sA[3][4096];      // [buf][128*32] Ah
    __shared__ unsigned short sB[3][2][2048];   // [buf][h/l][64*32]
    const int t = threadIdx.x;
    const int wave = t >> 6, lane = t & 63;
    const int lin = blockIdx.y * 24 + blockIdx.x;
    const int xcd = lin & 7, idx = lin >> 3;         // idx 0..71
    const int bx = xcd * 3 + (idx % 3);
    const int by = idx / 3;
    const int m0 = by * 128, n0 = bx * 64;
    const int wm = (wave >> 1) * 64, wn = (wave & 1) * 32;
    const int fr = lane & 15, quad = lane >> 4;

    f32x4 acc[4][2];
#pragma unroll
    for (int i = 0; i < 4; ++i)
#pragma unroll
        for (int j = 0; j < 2; ++j)
#pragma unroll
            for (int c = 0; c < 4; ++c) acc[i][j][c] = 0.f;

    const int sr = wave * 16 + (lane >> 2);
    const int sp = lane & 3;

    int offA[4], offB[2];
#pragma unroll
    for (int ti = 0; ti < 4; ++ti) {
        int ra = wm + ti * 16 + fr;
        offA[ti] = ra * 32 + ((quad ^ ((ra >> 1) & 3)) * 8);
    }
#pragma unroll
    for (int tj = 0; tj < 2; ++tj) {
        int rb = wn + tj * 16 + fr;
        offB[tj] = rb * 32 + ((quad ^ ((rb >> 1) & 3)) * 8);
    }

    const int nsteps = K >> 5;

// 4 cp16 per thread per stage (uniform across waves -> vmcnt counting valid)
#define STAGE(k0, buf)                                                        \
    {                                                                         \
        _Pragma("unroll")                                                     \
        for (int half = 0; half < 2; ++half) {                                \
            int r = sr + half * 64;                                           \
            int q = sp ^ ((r >> 1) & 3);                                      \
            size_t goA = (size_t)(m0 + r) * K + (k0) + q * 8;                 \
            cp16(Ah + goA, &sA[buf][half * 2048 + wave * 512]);               \
        }                                                                     \
        {                                                                     \
            int q = sp ^ ((sr >> 1) & 3);                                     \
            size_t goB = (size_t)(n0 + sr) * K + (k0) + q * 8;                \
            cp16(Bh + goB, &sB[buf][0][wave * 512]);                          \
            cp16(Bl + goB, &sB[buf][1][wave * 512]);                          \
        }                                                                     \
    }

    STAGE(0, 0);
    if (nsteps > 1) STAGE(32, 1);
    for (int s = 0; s < nsteps; ++s) {
        const int buf = s % 3;
        // stage(s) is the oldest in-flight group; stage(s+1) (4 loads/thread)
        // may stay in flight across the barrier.
        if (s + 1 < nsteps)
            asm volatile("s_waitcnt vmcnt(4)" ::: "memory");
        else
            asm volatile("s_waitcnt vmcnt(0)" ::: "memory");
        __builtin_amdgcn_s_barrier();
        __builtin_amdgcn_sched_barrier(0);   // pin: no stage issue above barrier
        if (s + 2 < nsteps) STAGE((s + 2) * 32, (s + 2) % 3);

        bf16x8 fah[4], fbh[2], fbl[2];
#pragma unroll
        for (int ti = 0; ti < 4; ++ti)
            fah[ti] = *(const bf16x8*)&sA[buf][offA[ti]];
#pragma unroll
        for (int tj = 0; tj < 2; ++tj) {
            fbh[tj] = *(const bf16x8*)&sB[buf][0][offB[tj]];
            fbl[tj] = *(const bf16x8*)&sB[buf][1][offB[tj]];
        }
#pragma unroll
        for (int ti = 0; ti < 4; ++ti)
#pragma unroll
            for (int tj = 0; tj < 2; ++tj)
                acc[ti][tj] = __builtin_amdgcn_mfma_f32_16x16x32_bf16(
                    fah[ti], fbh[tj], acc[ti][tj], 0, 0, 0);
#pragma unroll
        for (int ti = 0; ti < 4; ++ti)
#pragma unroll
            for (int tj = 0; tj < 2; ++tj)
                acc[ti][tj] = __builtin_amdgcn_mfma_f32_16x16x32_bf16(
                    fah[ti], fbl[tj], acc[ti][tj], 0, 0, 0);
    }
#undef STAGE

#pragma unroll
    for (int ti = 0; ti < 4; ++ti) {
        int rowb = m0 + wm + ti * 16 + quad * 4;
#pragma unroll
        for (int tj = 0; tj < 2; ++tj) {
            int col = n0 + wn + tj * 16 + fr;
            float bb = bias ? bias[col] : 0.f;
#pragma unroll
            for (int j2 = 0; j2 < 4; ++j2)
                C[(size_t)(rowb + j2) * N + col] = acc[ti][tj][j2] + bb;
        }
    }
}

// ---------------------------------------------------------------------------
// Generic fp32 GEMM (rel_k = pos_embed @ Wrel; K=192). 64x64 tiles so the
// grid is 384 blocks (was 96 at 128x128 -> 0.375 blocks/CU).
// ---------------------------------------------------------------------------
__global__ __launch_bounds__(256) void gemm_f32(
    const float* __restrict__ A, const float* __restrict__ B,
    const float* __restrict__ bias, float* __restrict__ C,
    int M, int N, int K, float alpha)
{
    __shared__ float As_[16][68];
    __shared__ float Bs_[16][68];
    const int t = threadIdx.x;
    const int m0 = blockIdx.y * 64;
    const int n0 = blockIdx.x * 64;
    const int tm = t >> 4, tn = t & 15;
    float acc[4][4];
#pragma unroll
    for (int i = 0; i < 4; ++i)
#pragma unroll
        for (int j = 0; j < 4; ++j) acc[i][j] = 0.f;

    for (int k0 = 0; k0 < K; k0 += 16) {
        {
            int row = t >> 2;           // 0..63
            int kk  = (t & 3) * 4;
            int gm  = m0 + row;
            float4 av = make_float4(0.f, 0.f, 0.f, 0.f);
            if (gm < M) av = *(const float4*)(A + (size_t)gm * K + k0 + kk);
            As_[kk + 0][row] = av.x; As_[kk + 1][row] = av.y;
            As_[kk + 2][row] = av.z; As_[kk + 3][row] = av.w;
        }
        {
            int kk = t >> 4;            // 0..15
            int nn = (t & 15) * 4;
            float4 bv = *(const float4*)(B + (size_t)(k0 + kk) * N + n0 + nn);
            *(float4*)&Bs_[kk][nn] = bv;
        }
        __syncthreads();
#pragma unroll
        for (int kk = 0; kk < 16; ++kk) {
            float a[4], bb[4];
            *(float4*)&a[0]  = *(const float4*)&As_[kk][tm * 4];
            *(float4*)&bb[0] = *(const float4*)&Bs_[kk][tn * 4];
#pragma unroll
            for (int i = 0; i < 4; ++i)
#pragma unroll
                for (int j = 0; j < 4; ++j)
                    acc[i][j] = fmaf(a[i], bb[j], acc[i][j]);
        }
        __syncthreads();
    }
#pragma unroll
    for (int i = 0; i < 4; ++i) {
        int gm = m0 + tm * 4 + i;
        if (gm < M) {
            float* crow = C + (size_t)gm * N + n0 + tn * 4;
#pragma unroll
            for (int j = 0; j < 4; ++j) {
                float vv = acc[i][j] * alpha;
                if (bias) vv += bias[n0 + tn * 4 + j];
                crow[j] = vv;
            }
        }
    }
}

// ---------------------------------------------------------------------------
// drk[h][jj] = sum_d (rpb[h,d]-rcb[h,d]) * rk[jj, h*64+d]
// ---------------------------------------------------------------------------
__global__ __launch_bounds__(256) void drk_kernel(
    const float* __restrict__ rkk, const float* __restrict__ cb,
    const float* __restrict__ rb, float* __restrict__ drk)
{
    int idx = blockIdx.x * 256 + threadIdx.x;
    if (idx >= 8 * RLEN) return;
    int jj = idx >> 3, h = idx & 7;
    const float* rrow = rkk + (size_t)jj * RKLD + h * 64;
    float s0 = 0, s1 = 0, s2 = 0, s3 = 0;
#pragma unroll
    for (int d4 = 0; d4 < 16; ++d4) {
        float4 rv = *(const float4*)(rrow + d4 * 4);
        float dx = rb[h * 64 + d4 * 4 + 0] - cb[h * 64 + d4 * 4 + 0];
        float dy = rb[h * 64 + d4 * 4 + 1] - cb[h * 64 + d4 * 4 + 1];
        float dz = rb[h * 64 + d4 * 4 + 2] - cb[h * 64 + d4 * 4 + 2];
        float dw = rb[h * 64 + d4 * 4 + 3] - cb[h * 64 + d4 * 4 + 3];
        s0 = fmaf(dx, rv.x, s0); s1 = fmaf(dy, rv.y, s1);
        s2 = fmaf(dz, rv.z, s2); s3 = fmaf(dw, rv.w, s3);
    }
    drk[h * RLEN + jj] = (s0 + s1) + (s2 + s3);
}

// ---------------------------------------------------------------------------
// Banded rel logits via MFMA (3-term split ≈ fp32), stored SHIFTED+TRANSPOSED
// bf16: relbT[bh][bi][jl][r], jl = ccg - 127 + r, ccg = ct*128 + cc_local.
// rk band rows staged split-bf16 (KSWZ); Q+rpb fragments in registers.
// ---------------------------------------------------------------------------
__global__ __launch_bounds__(256) void relb_mfma(
    const float* __restrict__ qkv, const float* __restrict__ rkk,
    const float* __restrict__ rb, unsigned short* __restrict__ relbT)
{
    __shared__ unsigned short sRh[8192];   // 128 band rows x 64 d (hi)
    __shared__ unsigned short sRl[8192];   // (lo)
    const int ct = blockIdx.x, bi = blockIdx.y, bh = blockIdx.z;
    const int b = bh >> 3, h = bh & 7;
    const int i0 = bi * 128;
    const int c0 = (bi == 0) ? 0 : (bi - 1) * 128;
    const int jjbase = c0 - i0 - 127 + (NSEQ - 1) + ct * 128;  // in [1280,1920)
    const int t = threadIdx.x;
    const int wave = t >> 6, lane = t & 63;
    const int fr = lane & 15, quad = lane >> 4;

    // ---- stage rk band (split bf16, swizzled [cc][64]) ----
#pragma unroll
    for (int it = 0; it < 8; ++it) {
        int lin = it * 256 + t;            // 0..2047
        int row = lin >> 4, d4 = (lin & 15) * 4;
        const float* rp = rkk + (size_t)(jjbase + row) * RKLD + h * 64 + d4;
        float4 v = *(const float4*)rp;
        ushort4 hh, ll;
        hh.x = f2bf(v.x); ll.x = f2bf(v.x - bf2f(hh.x));
        hh.y = f2bf(v.y); ll.y = f2bf(v.y - bf2f(hh.y));
        hh.z = f2bf(v.z); ll.z = f2bf(v.z - bf2f(hh.z));
        hh.w = f2bf(v.w); ll.w = f2bf(v.w - bf2f(hh.w));
        int o = KSWZ(row, d4);
        *(ushort4*)&sRh[o] = hh;
        *(ushort4*)&sRl[o] = ll;
    }
    // ---- Q + rel-pos-bias fragments (split bf16) ----
    bf16x8 qh[2][2], ql[2][2];
    {
        const float* Qg = qkv + ((size_t)(b * NSEQ + i0)) * HD3 + h * 64;
#pragma unroll
        for (int ti = 0; ti < 2; ++ti)
#pragma unroll
            for (int kc = 0; kc < 2; ++kc) {
                int m = wave * 32 + ti * 16 + fr;
                int k8 = kc * 32 + quad * 8;
                const float* qp = Qg + (size_t)m * HD3 + k8;
                const float* cp = rb + h * 64 + k8;
                float4 qa = *(const float4*)qp,  qb = *(const float4*)(qp + 4);
                float4 ca = *(const float4*)cp,  c2 = *(const float4*)(cp + 4);
                float vals[8] = {qa.x + ca.x, qa.y + ca.y, qa.z + ca.z, qa.w + ca.w,
                                 qb.x + c2.x, qb.y + c2.y, qb.z + c2.z, qb.w + c2.w};
                short hx[8], lx[8];
#pragma unroll
                for (int u = 0; u < 8; ++u) {
                    unsigned short hb = f2bf(vals[u]);
                    hx[u] = (short)hb;
                    lx[u] = (short)f2bf(vals[u] - bf2f(hb));
                }
                qh[ti][kc] = *(bf16x8*)hx;
                ql[ti][kc] = *(bf16x8*)lx;
            }
    }
    __syncthreads();

    // ---- S = (Q+rpb) · rk^T, 3-term split ----
    f32x4 sacc[2][8];
#pragma unroll
    for (int i = 0; i < 2; ++i)
#pragma unroll
        for (int j = 0; j < 8; ++j)
#pragma unroll
            for (int c = 0; c < 4; ++c) sacc[i][j][c] = 0.f;

#pragma unroll
    for (int seg = 0; seg < 3; ++seg) {
        const unsigned short* Rb = (seg == 1) ? sRl : sRh;
#pragma unroll
        for (int kc = 0; kc < 2; ++kc) {
            bf16x8 bv[8];
#pragma unroll
            for (int tj = 0; tj < 8; ++tj)
                bv[tj] = *(const bf16x8*)&Rb[KSWZ(tj * 16 + fr, kc * 32 + quad * 8)];
#pragma unroll
            for (int ti = 0; ti < 2; ++ti) {
                bf16x8 av = (seg == 2) ? ql[ti][kc] : qh[ti][kc];
#pragma unroll
                for (int tj = 0; tj < 8; ++tj)
                    sacc[ti][tj] = __builtin_amdgcn_mfma_f32_16x16x32_bf16(
                        av, bv[tj], sacc[ti][tj], 0, 0, 0);
            }
        }
    }

    // ---- shifted scatter-store to relbT ----
    size_t bb_ = ((size_t)bh * NB + bi) * 512;
#pragma unroll
    for (int ti = 0; ti < 2; ++ti) {
        int mr = wave * 32 + ti * 16 + quad * 4;
#pragma unroll
        for (int tj = 0; tj < 8; ++tj) {
            int ccg = ct * 128 + tj * 16 + fr;
#pragma unroll
            for (int reg = 0; reg < 4; ++reg) {
                int r = mr + reg;
                int jl = ccg - 127 + r;            // < 512 always
                if (jl >= 0)
                    relbT[(bb_ + jl) * 128 + r] = f2bf(sacc[ti][tj][reg]);
            }
        }
    }
}

// ---------------------------------------------------------------------------
// MFMA flash attention (local window). WG per (ct, bi, bh), 4 waves.
// ---------------------------------------------------------------------------
__global__ __launch_bounds__(256) void attn_mfma(
    const float* __restrict__ qkv, const unsigned short* __restrict__ relbT,
    const float* __restrict__ cb, float* __restrict__ O_part,
    float* __restrict__ l_part)
{
    __shared__ unsigned short sKP[16384];       // Kh[0:8192]+Kl[8192:] -> P[128][128]
    __shared__ unsigned short sVh[64 * VSTR];
    __shared__ unsigned short sVl[64 * VSTR];
    const int ct = blockIdx.x, bi = blockIdx.y, bh = blockIdx.z;
    const int b = bh >> 3, h = bh & 7;
    const int i0 = bi * 128;
    const int c0 = (bi == 0) ? 0 : (bi - 1) * 128;
    const int c1 = (bi == NB - 1) ? NSEQ : (bi + 2) * 128;
    const int ctile = c0 + ct * 128;
    const int t = threadIdx.x;
    const int wave = t >> 6, lane = t & 63;
    const int fr = lane & 15, quad = lane >> 4;

    float* Op = O_part + (((size_t)ct * 16 + bh) * NSEQ + i0) * 64;
    float* lp = l_part + ((size_t)ct * 16 + bh) * NSEQ + i0;

    if (ctile >= c1) {      // inactive edge tile: zero slice
        for (int k2 = t; k2 < 8192; k2 += 256) Op[k2] = 0.f;
        if (t < 128) lp[t] = 0.f;
        return;
    }

    // ---- stage K (split bf16, swizzled [j][64]) ----
    {
        const float* Kg = qkv + ((size_t)(b * NSEQ + ctile)) * HD3 + 512 + h * 64;
#pragma unroll
        for (int it = 0; it < 8; ++it) {
            int lin = it * 256 + t;            // 0..2047
            int row = lin >> 4, d4 = (lin & 15) * 4;
            float4 v = *(const float4*)(Kg + (size_t)row * HD3 + d4);
            ushort4 hh, ll;
            hh.x = f2bf(v.x); ll.x = f2bf(v.x - bf2f(hh.x));
            hh.y = f2bf(v.y); ll.y = f2bf(v.y - bf2f(hh.y));
            hh.z = f2bf(v.z); ll.z = f2bf(v.z - bf2f(hh.z));
            hh.w = f2bf(v.w); ll.w = f2bf(v.w - bf2f(hh.w));
            int o = KSWZ(row, d4);
            *(ushort4*)&sKP[o] = hh;
            *(ushort4*)&sKP[8192 + o] = ll;
        }
    }
    // ---- stage V transposed (split bf16, [d][VSTR]) ----
    {
        const float* Vg = qkv + ((size_t)(b * NSEQ + ctile)) * HD3 + 1024 + h * 64;
#pragma unroll
        for (int it = 0; it < 2; ++it) {
            int lin = it * 256 + t;            // 0..511
            int r4 = (lin >> 4) * 4, d4 = (lin & 15) * 4;
            float4 v0 = *(const float4*)(Vg + (size_t)(r4 + 0) * HD3 + d4);
            float4 v1 = *(const float4*)(Vg + (size_t)(r4 + 1) * HD3 + d4);
            float4 v2 = *(const float4*)(Vg + (size_t)(r4 + 2) * HD3 + d4);
            float4 v3 = *(const float4*)(Vg + (size_t)(r4 + 3) * HD3 + d4);
            const float* p0 = (const float*)&v0;
            const float* p1 = (const float*)&v1;
            const float* p2 = (const float*)&v2;
            const float* p3 = (const float*)&v3;
#pragma unroll
            for (int dd = 0; dd < 4; ++dd) {
                float a0 = p0[dd], a1 = p1[dd], a2 = p2[dd], a3 = p3[dd];
                ushort4 hh, ll;
                hh.x = f2bf(a0); ll.x = f2bf(a0 - bf2f(hh.x));
                hh.y = f2bf(a1); ll.y = f2bf(a1 - bf2f(hh.y));
                hh.z = f2bf(a2); ll.z = f2bf(a2 - bf2f(hh.z));
                hh.w = f2bf(a3); ll.w = f2bf(a3 - bf2f(hh.w));
                int o = (d4 + dd) * VSTR + r4;
                *(ushort4*)&sVh[o] = hh;
                *(ushort4*)&sVl[o] = ll;
            }
        }
    }
    // ---- Q fragments in registers (q + content bias, split bf16) ----
    bf16x8 qh[2][2], ql[2][2];
    {
        const float* Qg = qkv + ((size_t)(b * NSEQ + i0)) * HD3 + h * 64;
#pragma unroll
        for (int ti = 0; ti < 2; ++ti)
#pragma unroll
            for (int kc = 0; kc < 2; ++kc) {
                int m = wave * 32 + ti * 16 + fr;
                int k8 = kc * 32 + quad * 8;
                const float* qp = Qg + (size_t)m * HD3 + k8;
                const float* cp = cb + h * 64 + k8;
                float4 qa = *(const float4*)qp,  qb = *(const float4*)(qp + 4);
                float4 ca = *(const float4*)cp,  c2 = *(const float4*)(cp + 4);
                float vals[8] = {qa.x + ca.x, qa.y + ca.y, qa.z + ca.z, qa.w + ca.w,
                                 qb.x + c2.x, qb.y + c2.y, qb.z + c2.z, qb.w + c2.w};
                short hx[8], lx[8];
#pragma unroll
                for (int u = 0; u < 8; ++u) {
                    unsigned short hb = f2bf(vals[u]);
                    hx[u] = (short)hb;
                    lx[u] = (short)f2bf(vals[u] - bf2f(hb));
                }
                qh[ti][kc] = *(bf16x8*)hx;
                ql[ti][kc] = *(bf16x8*)lx;
            }
    }
    __syncthreads();

    // ---- S = Q K^T (3-term split), C-layout acc ----
    f32x4 sacc[2][8];
#pragma unroll
    for (int i = 0; i < 2; ++i)
#pragma unroll
        for (int j = 0; j < 8; ++j)
#pragma unroll
            for (int c = 0; c < 4; ++c) sacc[i][j][c] = 0.f;

#pragma unroll
    for (int seg = 0; seg < 3; ++seg) {
        const unsigned short* Kbase = sKP + ((seg == 1) ? 8192 : 0);
#pragma unroll
        for (int kc = 0; kc < 2; ++kc) {
            bf16x8 bv[8];
#pragma unroll
            for (int tj = 0; tj < 8; ++tj)
                bv[tj] = *(const bf16x8*)&Kbase[KSWZ(tj * 16 + fr, kc * 32 + quad * 8)];
#pragma unroll
            for (int ti = 0; ti < 2; ++ti) {
                bf16x8 av = (seg == 2) ? ql[ti][kc] : qh[ti][kc];
#pragma unroll
                for (int tj = 0; tj < 8; ++tj)
                    sacc[ti][tj] = __builtin_amdgcn_mfma_f32_16x16x32_bf16(
                        av, bv[tj], sacc[ti][tj], 0, 0, 0);
            }
        }
    }
    __syncthreads();   // all waves done reading K before P overwrites it

    // ---- rel + exp -> P (bf16, swizzled [r][j]); row-sums ----
    const unsigned short* relbase = relbT + (((size_t)bh * NB + bi) * 512 + ct * 128) * 128;
    float lsum[2][4] = {{0.f, 0.f, 0.f, 0.f}, {0.f, 0.f, 0.f, 0.f}};
#pragma unroll
    for (int ti = 0; ti < 2; ++ti) {
        int mr = wave * 32 + ti * 16 + quad * 4;
#pragma unroll
        for (int tj = 0; tj < 8; ++tj) {
            int j = tj * 16 + fr;
            ushort4 rl = *(const ushort4*)&relbase[(size_t)j * 128 + mr];
            unsigned short rr[4] = {rl.x, rl.y, rl.z, rl.w};
#pragma unroll
            for (int reg = 0; reg < 4; ++reg) {
                int r = mr + reg;
                float p = __expf(sacc[ti][tj][reg] + bf2f(rr[reg]));
                unsigned short pb = f2bf(p);
                lsum[ti][reg] += bf2f(pb);     // l consistent with bf16 P
                sKP[PSWZ(r, j)] = pb;
            }
        }
    }
#pragma unroll
    for (int m2 = 1; m2 < 16; m2 <<= 1)
#pragma unroll
        for (int ti = 0; ti < 2; ++ti)
#pragma unroll
            for (int reg = 0; reg < 4; ++reg)
                lsum[ti][reg] += __shfl_xor(lsum[ti][reg], m2, 64);
    if (fr == 0) {
#pragma unroll
        for (int ti = 0; ti < 2; ++ti) {
            int mr = wave * 32 + ti * 16 + quad * 4;
#pragma unroll
            for (int reg = 0; reg < 4; ++reg)
                lp[mr + reg] = lsum[ti][reg];
        }
    }

    // ---- O^T = Vt x P^T  (each wave consumes only its own P rows) ----
    f32x4 oacc[4][2];
#pragma unroll
    for (int i = 0; i < 4; ++i)
#pragma unroll
        for (int j = 0; j < 2; ++j)
#pragma unroll
            for (int c = 0; c < 4; ++c) oacc[i][j][c] = 0.f;

#pragma unroll
    for (int kc = 0; kc < 4; ++kc) {
        bf16x8 pbv[2];
#pragma unroll
        for (int rt2 = 0; rt2 < 2; ++rt2) {
            int r = (wave * 2 + rt2) * 16 + fr;
            pbv[rt2] = *(const bf16x8*)&sKP[PSWZ(r, kc * 32 + quad * 8)];
        }
#pragma unroll
        for (int dt = 0; dt < 4; ++dt) {
            int aoff = (dt * 16 + fr) * VSTR + kc * 32 + quad * 8;
            bf16x8 avh = *(const bf16x8*)&sVh[aoff];
            bf16x8 avl = *(const bf16x8*)&sVl[aoff];
#pragma unroll
            for (int rt2 = 0; rt2 < 2; ++rt2) {
                oacc[dt][rt2] = __builtin_amdgcn_mfma_f32_16x16x32_bf16(
                    avh, pbv[rt2], oacc[dt][rt2], 0, 0, 0);
                oacc[dt][rt2] = __builtin_amdgcn_mfma_f32_16x16x32_bf16(
                    avl, pbv[rt2], oacc[dt][rt2], 0, 0, 0);
            }
        }
    }
#pragma unroll
    for (int dt = 0; dt < 4; ++dt)
#pragma unroll
        for (int rt2 = 0; rt2 < 2; ++rt2) {
            int r = (wave * 2 + rt2) * 16 + fr;
            int d = dt * 16 + quad * 4;
            float4 ov = make_float4(oacc[dt][rt2][0], oacc[dt][rt2][1],
                                    oacc[dt][rt2][2], oacc[dt][rt2][3]);
            *(float4*)(Op + (size_t)r * 64 + d) = ov;
        }
}

// ---------------------------------------------------------------------------
// Global-column contribution (cols 0..3) for bi>=2: RMW into slice 0.
// ---------------------------------------------------------------------------
__global__ __launch_bounds__(128) void attn_gcols(
    const float* __restrict__ qkv, const float* __restrict__ rkk,
    const float* __restrict__ drk, const float* __restrict__ cb,
    float* __restrict__ O_part, float* __restrict__ l_part)
{
    const int bi = blockIdx.x + 2, bh = blockIdx.y;
    const int b = bh >> 3, h = bh & 7;
    const int i = bi * 128 + threadIdx.x;
    float qc[64];
    {
        const float* qrow = qkv + (size_t)(b * NSEQ + i) * HD3 + h * 64;
#pragma unroll
        for (int d4 = 0; d4 < 16; ++d4) {
            float4 qv = *(const float4*)(qrow + d4 * 4);
            float4 cv = *(const float4*)(cb + h * 64 + d4 * 4);
            qc[4 * d4 + 0] = qv.x + cv.x;
            qc[4 * d4 + 1] = qv.y + cv.y;
            qc[4 * d4 + 2] = qv.z + cv.z;
            qc[4 * d4 + 3] = qv.w + cv.w;
        }
    }
    float O[64];
#pragma unroll
    for (int d = 0; d < 64; ++d) O[d] = 0.f;
    float l = 0.f;
    for (int j = 0; j < 4; ++j) {
        const float* krow = qkv + ((size_t)(b * NSEQ + j)) * HD3 + 512 + h * 64;
        int jj = j - i + (NSEQ - 1);
        const float* rrow = rkk + (size_t)jj * RKLD + h * 64;
        float s0 = 0, s1 = 0, s2 = 0, s3 = 0;
#pragma unroll
        for (int d4 = 0; d4 < 16; ++d4) {
            float4 kv = *(const float4*)(krow + d4 * 4);
            float4 rv = *(const float4*)(rrow + d4 * 4);
            s0 = fmaf(qc[4 * d4 + 0], kv.x + rv.x, s0);
            s1 = fmaf(qc[4 * d4 + 1], kv.y + rv.y, s1);
            s2 = fmaf(qc[4 * d4 + 2], kv.z + rv.z, s2);
            s3 = fmaf(qc[4 * d4 + 3], kv.w + rv.w, s3);
        }
        float p = __expf((s0 + s1) + (s2 + s3) + drk[h * RLEN + jj]);
        l += p;
        const float* vrow = krow + 512;
#pragma unroll
        for (int d4 = 0; d4 < 16; ++d4) {
            float4 vf = *(const float4*)(vrow + d4 * 4);
            O[4 * d4 + 0] = fmaf(p, vf.x, O[4 * d4 + 0]);
            O[4 * d4 + 1] = fmaf(p, vf.y, O[4 * d4 + 1]);
            O[4 * d4 + 2] = fmaf(p, vf.z, O[4 * d4 + 2]);
            O[4 * d4 + 3] = fmaf(p, vf.w, O[4 * d4 + 3]);
        }
    }
    float* Op = O_part + ((size_t)bh * NSEQ + i) * 64;   // slice 0
#pragma unroll
    for (int d4 = 0; d4 < 16; ++d4) {
        float4 cur = *(float4*)(Op + d4 * 4);
        cur.x += O[4 * d4 + 0]; cur.y += O[4 * d4 + 1];
        cur.z += O[4 * d4 + 2]; cur.w += O[4 * d4 + 3];
        *(float4*)(Op + d4 * 4) = cur;
    }
    l_part[(size_t)bh * NSEQ + i] += l;
}

// ---------------------------------------------------------------------------
// Global-ROW attention partials: grid (12 col-chunks, 64 bhi), 256 thr.
// ---------------------------------------------------------------------------
__global__ __launch_bounds__(256) void grows_part(
    const float* __restrict__ qkv, const float* __restrict__ rkk,
    const float* __restrict__ drk, const float* __restrict__ cb,
    float* __restrict__ g_O, float* __restrict__ g_l)
{
    __shared__ float qc_s[64];
    __shared__ float p_s[128];
    __shared__ float obuf[4][64];
    __shared__ float lred[2];
    const int chunk = blockIdx.x;        // 0..11
    const int bhi = blockIdx.y;          // 0..63
    const int i = bhi & 3, h = (bhi >> 2) & 7, b = bhi >> 5;
    const int t = threadIdx.x;
    const int c0 = chunk * 128;
    if (t < 64)
        qc_s[t] = qkv[(size_t)(b * NSEQ + i) * HD3 + h * 64 + t] + cb[h * 64 + t];
    __syncthreads();
    if (t < 128) {
        int j = c0 + t;
        const float* krow = qkv + (size_t)(b * NSEQ + j) * HD3 + 512 + h * 64;
        int jj = j - i + (NSEQ - 1);
        const float* rrow = rkk + (size_t)jj * RKLD + h * 64;
        float s0 = 0, s1 = 0, s2 = 0, s3 = 0;
#pragma unroll
        for (int d4 = 0; d4 < 16; ++d4) {
            float4 kv = *(const float4*)(krow + d4 * 4);
            float4 rv = *(const float4*)(rrow + d4 * 4);
            float4 qv = *(const float4*)(&qc_s[d4 * 4]);
            s0 = fmaf(qv.x, kv.x + rv.x, s0);
            s1 = fmaf(qv.y, kv.y + rv.y, s1);
            s2 = fmaf(qv.z, kv.z + rv.z, s2);
            s3 = fmaf(qv.w, kv.w + rv.w, s3);
        }
        float p = __expf((s0 + s1) + (s2 + s3) + drk[h * RLEN + jj]);
        p_s[t] = p;
        float ls = p;
#pragma unroll
        for (int off = 32; off > 0; off >>= 1)
            ls += __shfl_down(ls, off, 64);
        if ((t & 63) == 0) lred[t >> 6] = ls;
    }
    __syncthreads();
    {
        const int d = t & 63, g = t >> 6;
        float a0 = 0, a1 = 0;
        const float* vbase = qkv + (size_t)(b * NSEQ + c0 + g * 32) * HD3 + 1024 + h * 64 + d;
#pragma unroll
        for (int j2 = 0; j2 < 32; j2 += 2) {
            a0 = fmaf(p_s[g * 32 + j2],     vbase[(size_t)j2 * HD3],       a0);
            a1 = fmaf(p_s[g * 32 + j2 + 1], vbase[(size_t)(j2 + 1) * HD3], a1);
        }
        obuf[g][d] = a0 + a1;
    }
    __syncthreads();
    if (t < 64) {
        float o = (obuf[0][t] + obuf[1][t]) + (obuf[2][t] + obuf[3][t]);
        g_O[((size_t)chunk * 64 + bhi) * 64 + t] = o;
        if (t == 0) g_l[chunk * 64 + bhi] = lred[0] + lred[1];
    }
}

// ---------------------------------------------------------------------------
// Merge 3 ct-slices, normalize, emit ao as bf16 (hi only; 2-term out-proj).
// Rows i<4 (global rows) take their (O,l) from the 12 grows_part chunks.
// ---------------------------------------------------------------------------
__global__ __launch_bounds__(256) void norm_merge(
    const float* __restrict__ O_part, const float* __restrict__ l_part,
    const float* __restrict__ g_O, const float* __restrict__ g_l,
    unsigned short* __restrict__ aoh)
{
    const int bh = blockIdx.y, b = bh >> 3, h = bh & 7;
    const int i = blockIdx.x * 16 + (threadIdx.x >> 4);
    const int d4 = threadIdx.x & 15;
    float ox = 0, oy = 0, oz = 0, ow = 0, l = 0;
    if (i < 4) {          // global row: sum the 12 column-chunk partials
        const int bhi = bh * 4 + i;
#pragma unroll
        for (int c = 0; c < 12; ++c) {
            const float* gp = g_O + ((size_t)c * 64 + bhi) * 64 + d4 * 4;
            ox += gp[0]; oy += gp[1]; oz += gp[2]; ow += gp[3];
            l += g_l[c * 64 + bhi];
        }
    } else {
#pragma unroll
        for (int s = 0; s < 3; ++s) {
            const float* Opp = O_part + (((size_t)s * 16 + bh) * NSEQ + i) * 64 + d4 * 4;
            float4 p = *(const float4*)Opp;
            ox += p.x; oy += p.y; oz += p.z; ow += p.w;
            l += l_part[((size_t)s * 16 + bh) * NSEQ + i];
        }
    }
    float inv = 1.f / l;
    ushort4 hh;
    hh.x = f2bf(ox * inv); hh.y = f2bf(oy * inv);
    hh.z = f2bf(oz * inv); hh.w = f2bf(ow * inv);
    size_t o = ((size_t)(b * NSEQ + i)) * 512 + h * 64 + d4 * 4;
    *(ushort4*)(aoh + o) = hh;
}

// ---------------------------------------------------------------------------
extern "C" void kernel_launch(void* const* d_in, const int* in_sizes, int n_in,
                              void* d_out, int out_size, void* d_ws, size_t ws_size,
                              hipStream_t stream)
{
    const float* x    = (const float*)d_in[0];
    const float* Wq   = (const float*)d_in[1];
    const float* Wk   = (const float*)d_in[2];
    const float* Wv   = (const float*)d_in[3];
    const float* Wrel = (const float*)d_in[4];
    const float* cb   = (const float*)d_in[5];
    const float* rb   = (const float*)d_in[6];
    const float* Wo   = (const float*)d_in[7];
    const float* bo   = (const float*)d_in[8];
    const float* pe   = (const float*)d_in[9];
    float* out = (float*)d_out;

    float* ws = (float*)d_ws;
    float* qkv   = ws;                                   // [3072][1536] f32
    float* rkbuf = ws + 4718592;                         // [3071][512] f32
    float* drk   = ws + 6291456;                         // [8][3071] f32
    unsigned short* aoh = (unsigned short*)(ws + 6316032);   // [3072][512] bf16
    unsigned short* woh = (unsigned short*)(ws + 7888896);   // WoT [1536][512] bf16
    unsigned short* wol = (unsigned short*)(ws + 8282112);
    float* R = ws + 8675328;                             // aliased region
    unsigned short* relbT = (unsigned short*)R;              // [16][12][512][128] bf16
    unsigned short* xh  = (unsigned short*)R;                // dead before relbT written
    unsigned short* wqh = (unsigned short*)(R + 4718592);    // WqkvT [1536][1536] bf16
    unsigned short* wql = (unsigned short*)(R + 5898240);
    float* g_O = R + 6291456;                            // [12][64][64] f32 (after relbT)
    float* g_l = R + 6340608;                            // [12][64] f32
    float* O_part = ws + 15753216;                       // [3][16][1536][64] f32
    float* l_part = ws + 20471808;                       // [3][16][1536] f32

    dim3 blk(256);
    splitf_h<<<4608, blk, 0, stream>>>(x, xh, 1179648);
    wsplit_qkv<<<dim3(8, 24, 3), blk, 0, stream>>>(Wq, Wk, Wv, wqh, wql);
    wsplit_t<<<dim3(24, 8), blk, 0, stream>>>(Wo, woh, wol, 512, 1536, 0, 512, 1.f);
    gemm_mfma2<<<dim3(24, 24), blk, 0, stream>>>(xh, wqh, wql, nullptr, qkv,
                                                 3072, 1536, 1536);
    gemm_f32<<<dim3(8, 48), blk, 0, stream>>>(pe, Wrel, nullptr, rkbuf, 3071, 512, 192, 1.f);
    drk_kernel<<<96, blk, 0, stream>>>(rkbuf, cb, rb, drk);
    relb_mfma<<<dim3(4, 12, 16), blk, 0, stream>>>(qkv, rkbuf, rb, relbT);
    attn_mfma<<<dim3(3, 12, 16), blk, 0, stream>>>(qkv, relbT, cb, O_part, l_part);
    attn_gcols<<<dim3(10, 16), dim3(128), 0, stream>>>(qkv, rkbuf, drk, cb, O_part, l_part);
    grows_part<<<dim3(12, 64), blk, 0, stream>>>(qkv, rkbuf, drk, cb, g_O, g_l);
    norm_merge<<<dim3(96, 16), blk, 0, stream>>>(O_part, l_part, g_O, g_l, aoh);
    gemm_mfma2<<<dim3(24, 24), blk, 0, stream>>>(aoh, woh, wol, bo, out,
                                                 3072, 1536, 512);
}

// Round 2
// 271.728 us; speedup vs baseline: 1.1234x; 1.0701x over previous
//
#include <hip/hip_runtime.h>
#include <math.h>

#define NSEQ 1536
#define HD3  1536      // fused qkv row stride
#define RKLD 512       // rel_k row stride
#define RLEN 3071
#define NB   12

typedef __attribute__((ext_vector_type(8))) short bf16x8;
typedef __attribute__((ext_vector_type(4))) float f32x4;
typedef _Float16 f16x8 __attribute__((ext_vector_type(8)));

__device__ __forceinline__ unsigned short f2bf(float f) {
    union { float f; unsigned u; } v; v.f = f;
    unsigned r = v.u + 0x7fffu + ((v.u >> 16) & 1u);
    return (unsigned short)(r >> 16);
}
__device__ __forceinline__ float bf2f(unsigned short s) {
    union { unsigned u; float f; } v; v.u = ((unsigned)s) << 16;
    return v.f;
}
__device__ __forceinline__ void cp16(const void* g, void* l) {
    __builtin_amdgcn_global_load_lds(
        (const __attribute__((address_space(1))) void*)g,
        (__attribute__((address_space(3))) void*)l, 16, 0, 0);
}

// LDS swizzles: keep 8-elem chunks contiguous; XOR chunk id with row bits to
// break power-of-2 stride bank conflicts.
#define KSWZ(row, d) ((row) * 64 + (((((d) >> 3) ^ ((row) & 7))) << 3) + ((d) & 7))
#define PSWZ(r, j)   ((r) * 128 + (((((j) >> 3) ^ ((r) & 15))) << 3) + ((j) & 7))
#define VSTR 136     // Vt row stride in shorts (272B: 16B-aligned, non-pow2)

// ---------------------------------------------------------------------------
// fp32 -> f16 (single-term GEMM input)
// ---------------------------------------------------------------------------
__global__ __launch_bounds__(256) void splitf16(
    const float* __restrict__ X, _Float16* __restrict__ H, int n4)
{
    int i = blockIdx.x * 256 + threadIdx.x;
    if (i >= n4) return;
    float4 v = ((const float4*)X)[i];
    union { _Float16 h[4]; ushort4 u; } c;
    c.h[0] = (_Float16)v.x; c.h[1] = (_Float16)v.y;
    c.h[2] = (_Float16)v.z; c.h[3] = (_Float16)v.w;
    ((ushort4*)H)[i] = c.u;
}

// ---------------------------------------------------------------------------
// Weight transpose (generic): W[K][N] f32 -> T[n_off+N][ldt] f16
// ---------------------------------------------------------------------------
__device__ __forceinline__ void wsplit_body16(
    const float* __restrict__ W, _Float16* __restrict__ T,
    int K, int N, int n_off, int ldt, float scale, int bx, int by)
{
    __shared__ float tile[64][65];
    const int k0 = by * 64, n0 = bx * 64;
    const int t = threadIdx.x;
    const int rr = t >> 4, c4 = (t & 15) * 4;
#pragma unroll
    for (int p = 0; p < 4; ++p) {
        int r = p * 16 + rr;
        float4 v = *(const float4*)(W + (size_t)(k0 + r) * N + n0 + c4);
        tile[r][c4 + 0] = v.x; tile[r][c4 + 1] = v.y;
        tile[r][c4 + 2] = v.z; tile[r][c4 + 3] = v.w;
    }
    __syncthreads();
#pragma unroll
    for (int p = 0; p < 4; ++p) {
        int n = p * 16 + rr;
        union { _Float16 h[4]; ushort4 u; } cc;
        cc.h[0] = (_Float16)(tile[c4 + 0][n] * scale);
        cc.h[1] = (_Float16)(tile[c4 + 1][n] * scale);
        cc.h[2] = (_Float16)(tile[c4 + 2][n] * scale);
        cc.h[3] = (_Float16)(tile[c4 + 3][n] * scale);
        size_t o = (size_t)(n_off + n0 + n) * ldt + k0 + c4;
        *(ushort4*)(T + o) = cc.u;
    }
}

__global__ __launch_bounds__(256) void wsplit_qkv16(
    const float* __restrict__ Wq, const float* __restrict__ Wk,
    const float* __restrict__ Wv, _Float16* __restrict__ T)
{
    const int z = blockIdx.z;
    const float* W = (z == 0) ? Wq : (z == 1) ? Wk : Wv;
    wsplit_body16(W, T, 1536, 512, z * 512, 1536, (z == 0) ? 0.125f : 1.f,
                  blockIdx.x, blockIdx.y);
}

__global__ __launch_bounds__(256) void wsplit_t16(
    const float* __restrict__ W, _Float16* __restrict__ T,
    int K, int N, int n_off, int ldt, float scale)
{
    wsplit_body16(W, T, K, N, n_off, ldt, scale, blockIdx.x, blockIdx.y);
}

// ---------------------------------------------------------------------------
// Single-term f16 MFMA GEMM, 64x64 tile, BK=64: C = A·B^T (+bias).
// f16 (2^-12) beats the old bf16-hi A (2^-9) at HALF the MFMA/LDS work.
// Grid 1152 (4.5 blocks/CU, 90% balance) vs old 576 (2.25, 75%) attacks the
// latency-bound regime (nothing saturated at 51us: MFMA 22%, LDS 38%, HBM 15%).
// Proven 2-buffer single-barrier structure; 32KB LDS; KSWZ; XCD swizzle.
// ---------------------------------------------------------------------------
__global__ __launch_bounds__(256) void gemm_f16k(
    const _Float16* __restrict__ A,   // [M][K] f16
    const _Float16* __restrict__ B,   // [N][K] f16 (pre-transposed weight)
    const float* __restrict__ bias, float* __restrict__ C,
    int M, int N, int K)
{
    __shared__ _Float16 sA[2][4096];    // [buf][64*64]
    __shared__ _Float16 sB[2][4096];
    const int t = threadIdx.x;
    const int wave = t >> 6, lane = t & 63;
    // XCD-aware bijective swizzle (nwg % 8 == 0 for all launches here)
    const int nwg = gridDim.x * gridDim.y;
    const int lin = blockIdx.y * gridDim.x + blockIdx.x;
    const int swz = (lin & 7) * (nwg >> 3) + (lin >> 3);
    const int bx = swz % gridDim.x, by = swz / gridDim.x;
    const int m0 = by * 64, n0 = bx * 64;
    const int wm = (wave >> 1) * 32, wn = (wave & 1) * 32;
    const int fr = lane & 15, quad = lane >> 4;

    f32x4 acc[2][2];
#pragma unroll
    for (int i = 0; i < 2; ++i)
#pragma unroll
        for (int j = 0; j < 2; ++j)
#pragma unroll
            for (int c = 0; c < 4; ++c) acc[i][j][c] = 0.f;

    const int nsteps = K >> 6;

// 2 cp16 per array per thread per stage; LDS dest linear (wave base + lane*16B),
// global source pre-swizzled so LDS slot (row, c) holds chunk c^(row&7) (KSWZ).
#define STAGE(k0, buf)                                                        \
    {                                                                         \
        _Pragma("unroll")                                                     \
        for (int it = 0; it < 2; ++it) {                                      \
            int cidx = it * 256 + t;                                          \
            int row = cidx >> 3, slot = cidx & 7;                             \
            int gch = slot ^ (row & 7);                                       \
            size_t goA = (size_t)(m0 + row) * K + (k0) + gch * 8;             \
            size_t goB = (size_t)(n0 + row) * K + (k0) + gch * 8;             \
            cp16(A + goA, &sA[buf][it * 2048 + wave * 512]);                  \
            cp16(B + goB, &sB[buf][it * 2048 + wave * 512]);                  \
        }                                                                     \
    }

    STAGE(0, 0);
    for (int s = 0; s < nsteps; ++s) {
        const int buf = s & 1;
        __syncthreads();
        if (s + 1 < nsteps) STAGE((s + 1) * 64, buf ^ 1);

        f16x8 fa[2][2], fb[2][2];
#pragma unroll
        for (int ti = 0; ti < 2; ++ti)
#pragma unroll
            for (int kc = 0; kc < 2; ++kc) {
                fa[ti][kc] = *(const f16x8*)&sA[buf][KSWZ(wm + ti * 16 + fr,
                                                          kc * 32 + quad * 8)];
                fb[ti][kc] = *(const f16x8*)&sB[buf][KSWZ(wn + ti * 16 + fr,
                                                          kc * 32 + quad * 8)];
            }
#pragma unroll
        for (int ti = 0; ti < 2; ++ti)
#pragma unroll
            for (int tj = 0; tj < 2; ++tj)
#pragma unroll
                for (int kc = 0; kc < 2; ++kc)
                    acc[ti][tj] = __builtin_amdgcn_mfma_f32_16x16x32_f16(
                        fa[ti][kc], fb[tj][kc], acc[ti][tj], 0, 0, 0);
    }
#undef STAGE

#pragma unroll
    for (int ti = 0; ti < 2; ++ti) {
        int rowb = m0 + wm + ti * 16 + quad * 4;
#pragma unroll
        for (int tj = 0; tj < 2; ++tj) {
            int col = n0 + wn + tj * 16 + fr;
            float bb = bias ? bias[col] : 0.f;
#pragma unroll
            for (int j2 = 0; j2 < 4; ++j2)
                C[(size_t)(rowb + j2) * N + col] = acc[ti][tj][j2] + bb;
        }
    }
}

// ---------------------------------------------------------------------------
// Generic fp32 GEMM (rel_k = pos_embed @ Wrel; K=192), 64x64 tiles.
// ---------------------------------------------------------------------------
__global__ __launch_bounds__(256) void gemm_f32(
    const float* __restrict__ A, const float* __restrict__ B,
    const float* __restrict__ bias, float* __restrict__ C,
    int M, int N, int K, float alpha)
{
    __shared__ float As_[16][68];
    __shared__ float Bs_[16][68];
    const int t = threadIdx.x;
    const int m0 = blockIdx.y * 64;
    const int n0 = blockIdx.x * 64;
    const int tm = t >> 4, tn = t & 15;
    float acc[4][4];
#pragma unroll
    for (int i = 0; i < 4; ++i)
#pragma unroll
        for (int j = 0; j < 4; ++j) acc[i][j] = 0.f;

    for (int k0 = 0; k0 < K; k0 += 16) {
        {
            int row = t >> 2;           // 0..63
            int kk  = (t & 3) * 4;
            int gm  = m0 + row;
            float4 av = make_float4(0.f, 0.f, 0.f, 0.f);
            if (gm < M) av = *(const float4*)(A + (size_t)gm * K + k0 + kk);
            As_[kk + 0][row] = av.x; As_[kk + 1][row] = av.y;
            As_[kk + 2][row] = av.z; As_[kk + 3][row] = av.w;
        }
        {
            int kk = t >> 4;            // 0..15
            int nn = (t & 15) * 4;
            float4 bv = *(const float4*)(B + (size_t)(k0 + kk) * N + n0 + nn);
            *(float4*)&Bs_[kk][nn] = bv;
        }
        __syncthreads();
#pragma unroll
        for (int kk = 0; kk < 16; ++kk) {
            float a[4], bb[4];
            *(float4*)&a[0]  = *(const float4*)&As_[kk][tm * 4];
            *(float4*)&bb[0] = *(const float4*)&Bs_[kk][tn * 4];
#pragma unroll
            for (int i = 0; i < 4; ++i)
#pragma unroll
                for (int j = 0; j < 4; ++j)
                    acc[i][j] = fmaf(a[i], bb[j], acc[i][j]);
        }
        __syncthreads();
    }
#pragma unroll
    for (int i = 0; i < 4; ++i) {
        int gm = m0 + tm * 4 + i;
        if (gm < M) {
            float* crow = C + (size_t)gm * N + n0 + tn * 4;
#pragma unroll
            for (int j = 0; j < 4; ++j) {
                float vv = acc[i][j] * alpha;
                if (bias) vv += bias[n0 + tn * 4 + j];
                crow[j] = vv;
            }
        }
    }
}

// ---------------------------------------------------------------------------
// drk[h][jj] = sum_d (rpb[h,d]-rcb[h,d]) * rk[jj, h*64+d]
// ---------------------------------------------------------------------------
__global__ __launch_bounds__(256) void drk_kernel(
    const float* __restrict__ rkk, const float* __restrict__ cb,
    const float* __restrict__ rb, float* __restrict__ drk)
{
    int idx = blockIdx.x * 256 + threadIdx.x;
    if (idx >= 8 * RLEN) return;
    int jj = idx >> 3, h = idx & 7;
    const float* rrow = rkk + (size_t)jj * RKLD + h * 64;
    float s0 = 0, s1 = 0, s2 = 0, s3 = 0;
#pragma unroll
    for (int d4 = 0; d4 < 16; ++d4) {
        float4 rv = *(const float4*)(rrow + d4 * 4);
        float dx = rb[h * 64 + d4 * 4 + 0] - cb[h * 64 + d4 * 4 + 0];
        float dy = rb[h * 64 + d4 * 4 + 1] - cb[h * 64 + d4 * 4 + 1];
        float dz = rb[h * 64 + d4 * 4 + 2] - cb[h * 64 + d4 * 4 + 2];
        float dw = rb[h * 64 + d4 * 4 + 3] - cb[h * 64 + d4 * 4 + 3];
        s0 = fmaf(dx, rv.x, s0); s1 = fmaf(dy, rv.y, s1);
        s2 = fmaf(dz, rv.z, s2); s3 = fmaf(dw, rv.w, s3);
    }
    drk[h * RLEN + jj] = (s0 + s1) + (s2 + s3);
}

// ---------------------------------------------------------------------------
// Banded rel logits via MFMA (3-term split ≈ fp32), stored SHIFTED+TRANSPOSED
// bf16: relbT[bh][bi][jl][r], jl = ccg - 127 + r, ccg = ct*128 + cc_local.
// rk band rows staged split-bf16 (KSWZ); Q+rpb fragments in registers.
// ---------------------------------------------------------------------------
__global__ __launch_bounds__(256) void relb_mfma(
    const float* __restrict__ qkv, const float* __restrict__ rkk,
    const float* __restrict__ rb, unsigned short* __restrict__ relbT)
{
    __shared__ unsigned short sRh[8192];   // 128 band rows x 64 d (hi)
    __shared__ unsigned short sRl[8192];   // (lo)
    const int ct = blockIdx.x, bi = blockIdx.y, bh = blockIdx.z;
    const int b = bh >> 3, h = bh & 7;
    const int i0 = bi * 128;
    const int c0 = (bi == 0) ? 0 : (bi - 1) * 128;
    const int jjbase = c0 - i0 - 127 + (NSEQ - 1) + ct * 128;  // in [1280,1920)
    const int t = threadIdx.x;
    const int wave = t >> 6, lane = t & 63;
    const int fr = lane & 15, quad = lane >> 4;

    // ---- stage rk band (split bf16, swizzled [cc][64]) ----
#pragma unroll
    for (int it = 0; it < 8; ++it) {
        int lin = it * 256 + t;            // 0..2047
        int row = lin >> 4, d4 = (lin & 15) * 4;
        const float* rp = rkk + (size_t)(jjbase + row) * RKLD + h * 64 + d4;
        float4 v = *(const float4*)rp;
        ushort4 hh, ll;
        hh.x = f2bf(v.x); ll.x = f2bf(v.x - bf2f(hh.x));
        hh.y = f2bf(v.y); ll.y = f2bf(v.y - bf2f(hh.y));
        hh.z = f2bf(v.z); ll.z = f2bf(v.z - bf2f(hh.z));
        hh.w = f2bf(v.w); ll.w = f2bf(v.w - bf2f(hh.w));
        int o = KSWZ(row, d4);
        *(ushort4*)&sRh[o] = hh;
        *(ushort4*)&sRl[o] = ll;
    }
    // ---- Q + rel-pos-bias fragments (split bf16) ----
    bf16x8 qh[2][2], ql[2][2];
    {
        const float* Qg = qkv + ((size_t)(b * NSEQ + i0)) * HD3 + h * 64;
#pragma unroll
        for (int ti = 0; ti < 2; ++ti)
#pragma unroll
            for (int kc = 0; kc < 2; ++kc) {
                int m = wave * 32 + ti * 16 + fr;
                int k8 = kc * 32 + quad * 8;
                const float* qp = Qg + (size_t)m * HD3 + k8;
                const float* cp = rb + h * 64 + k8;
                float4 qa = *(const float4*)qp,  qb = *(const float4*)(qp + 4);
                float4 ca = *(const float4*)cp,  c2 = *(const float4*)(cp + 4);
                float vals[8] = {qa.x + ca.x, qa.y + ca.y, qa.z + ca.z, qa.w + ca.w,
                                 qb.x + c2.x, qb.y + c2.y, qb.z + c2.z, qb.w + c2.w};
                short hx[8], lx[8];
#pragma unroll
                for (int u = 0; u < 8; ++u) {
                    unsigned short hb = f2bf(vals[u]);
                    hx[u] = (short)hb;
                    lx[u] = (short)f2bf(vals[u] - bf2f(hb));
                }
                qh[ti][kc] = *(bf16x8*)hx;
                ql[ti][kc] = *(bf16x8*)lx;
            }
    }
    __syncthreads();

    // ---- S = (Q+rpb) · rk^T, 3-term split ----
    f32x4 sacc[2][8];
#pragma unroll
    for (int i = 0; i < 2; ++i)
#pragma unroll
        for (int j = 0; j < 8; ++j)
#pragma unroll
            for (int c = 0; c < 4; ++c) sacc[i][j][c] = 0.f;

#pragma unroll
    for (int seg = 0; seg < 3; ++seg) {
        const unsigned short* Rb = (seg == 1) ? sRl : sRh;
#pragma unroll
        for (int kc = 0; kc < 2; ++kc) {
            bf16x8 bv[8];
#pragma unroll
            for (int tj = 0; tj < 8; ++tj)
                bv[tj] = *(const bf16x8*)&Rb[KSWZ(tj * 16 + fr, kc * 32 + quad * 8)];
#pragma unroll
            for (int ti = 0; ti < 2; ++ti) {
                bf16x8 av = (seg == 2) ? ql[ti][kc] : qh[ti][kc];
#pragma unroll
                for (int tj = 0; tj < 8; ++tj)
                    sacc[ti][tj] = __builtin_amdgcn_mfma_f32_16x16x32_bf16(
                        av, bv[tj], sacc[ti][tj], 0, 0, 0);
            }
        }
    }

    // ---- shifted scatter-store to relbT ----
    size_t bb_ = ((size_t)bh * NB + bi) * 512;
#pragma unroll
    for (int ti = 0; ti < 2; ++ti) {
        int mr = wave * 32 + ti * 16 + quad * 4;
#pragma unroll
        for (int tj = 0; tj < 8; ++tj) {
            int ccg = ct * 128 + tj * 16 + fr;
#pragma unroll
            for (int reg = 0; reg < 4; ++reg) {
                int r = mr + reg;
                int jl = ccg - 127 + r;            // < 512 always
                if (jl >= 0)
                    relbT[(bb_ + jl) * 128 + r] = f2bf(sacc[ti][tj][reg]);
            }
        }
    }
}

// ---------------------------------------------------------------------------
// MFMA flash attention (local window). WG per (ct, bi, bh), 4 waves.
// ---------------------------------------------------------------------------
__global__ __launch_bounds__(256) void attn_mfma(
    const float* __restrict__ qkv, const unsigned short* __restrict__ relbT,
    const float* __restrict__ cb, float* __restrict__ O_part,
    float* __restrict__ l_part)
{
    __shared__ unsigned short sKP[16384];       // Kh[0:8192]+Kl[8192:] -> P[128][128]
    __shared__ unsigned short sVh[64 * VSTR];
    __shared__ unsigned short sVl[64 * VSTR];
    const int ct = blockIdx.x, bi = blockIdx.y, bh = blockIdx.z;
    const int b = bh >> 3, h = bh & 7;
    const int i0 = bi * 128;
    const int c0 = (bi == 0) ? 0 : (bi - 1) * 128;
    const int c1 = (bi == NB - 1) ? NSEQ : (bi + 2) * 128;
    const int ctile = c0 + ct * 128;
    const int t = threadIdx.x;
    const int wave = t >> 6, lane = t & 63;
    const int fr = lane & 15, quad = lane >> 4;

    float* Op = O_part + (((size_t)ct * 16 + bh) * NSEQ + i0) * 64;
    float* lp = l_part + ((size_t)ct * 16 + bh) * NSEQ + i0;

    if (ctile >= c1) {      // inactive edge tile: zero slice
        for (int k2 = t; k2 < 8192; k2 += 256) Op[k2] = 0.f;
        if (t < 128) lp[t] = 0.f;
        return;
    }

    // ---- stage K (split bf16, swizzled [j][64]) ----
    {
        const float* Kg = qkv + ((size_t)(b * NSEQ + ctile)) * HD3 + 512 + h * 64;
#pragma unroll
        for (int it = 0; it < 8; ++it) {
            int lin = it * 256 + t;            // 0..2047
            int row = lin >> 4, d4 = (lin & 15) * 4;
            float4 v = *(const float4*)(Kg + (size_t)row * HD3 + d4);
            ushort4 hh, ll;
            hh.x = f2bf(v.x); ll.x = f2bf(v.x - bf2f(hh.x));
            hh.y = f2bf(v.y); ll.y = f2bf(v.y - bf2f(hh.y));
            hh.z = f2bf(v.z); ll.z = f2bf(v.z - bf2f(hh.z));
            hh.w = f2bf(v.w); ll.w = f2bf(v.w - bf2f(hh.w));
            int o = KSWZ(row, d4);
            *(ushort4*)&sKP[o] = hh;
            *(ushort4*)&sKP[8192 + o] = ll;
        }
    }
    // ---- stage V transposed (split bf16, [d][VSTR]) ----
    {
        const float* Vg = qkv + ((size_t)(b * NSEQ + ctile)) * HD3 + 1024 + h * 64;
#pragma unroll
        for (int it = 0; it < 2; ++it) {
            int lin = it * 256 + t;            // 0..511
            int r4 = (lin >> 4) * 4, d4 = (lin & 15) * 4;
            float4 v0 = *(const float4*)(Vg + (size_t)(r4 + 0) * HD3 + d4);
            float4 v1 = *(const float4*)(Vg + (size_t)(r4 + 1) * HD3 + d4);
            float4 v2 = *(const float4*)(Vg + (size_t)(r4 + 2) * HD3 + d4);
            float4 v3 = *(const float4*)(Vg + (size_t)(r4 + 3) * HD3 + d4);
            const float* p0 = (const float*)&v0;
            const float* p1 = (const float*)&v1;
            const float* p2 = (const float*)&v2;
            const float* p3 = (const float*)&v3;
#pragma unroll
            for (int dd = 0; dd < 4; ++dd) {
                float a0 = p0[dd], a1 = p1[dd], a2 = p2[dd], a3 = p3[dd];
                ushort4 hh, ll;
                hh.x = f2bf(a0); ll.x = f2bf(a0 - bf2f(hh.x));
                hh.y = f2bf(a1); ll.y = f2bf(a1 - bf2f(hh.y));
                hh.z = f2bf(a2); ll.z = f2bf(a2 - bf2f(hh.z));
                hh.w = f2bf(a3); ll.w = f2bf(a3 - bf2f(hh.w));
                int o = (d4 + dd) * VSTR + r4;
                *(ushort4*)&sVh[o] = hh;
                *(ushort4*)&sVl[o] = ll;
            }
        }
    }
    // ---- Q fragments in registers (q + content bias, split bf16) ----
    bf16x8 qh[2][2], ql[2][2];
    {
        const float* Qg = qkv + ((size_t)(b * NSEQ + i0)) * HD3 + h * 64;
#pragma unroll
        for (int ti = 0; ti < 2; ++ti)
#pragma unroll
            for (int kc = 0; kc < 2; ++kc) {
                int m = wave * 32 + ti * 16 + fr;
                int k8 = kc * 32 + quad * 8;
                const float* qp = Qg + (size_t)m * HD3 + k8;
                const float* cp = cb + h * 64 + k8;
                float4 qa = *(const float4*)qp,  qb = *(const float4*)(qp + 4);
                float4 ca = *(const float4*)cp,  c2 = *(const float4*)(cp + 4);
                float vals[8] = {qa.x + ca.x, qa.y + ca.y, qa.z + ca.z, qa.w + ca.w,
                                 qb.x + c2.x, qb.y + c2.y, qb.z + c2.z, qb.w + c2.w};
                short hx[8], lx[8];
#pragma unroll
                for (int u = 0; u < 8; ++u) {
                    unsigned short hb = f2bf(vals[u]);
                    hx[u] = (short)hb;
                    lx[u] = (short)f2bf(vals[u] - bf2f(hb));
                }
                qh[ti][kc] = *(bf16x8*)hx;
                ql[ti][kc] = *(bf16x8*)lx;
            }
    }
    __syncthreads();

    // ---- S = Q K^T (3-term split), C-layout acc ----
    f32x4 sacc[2][8];
#pragma unroll
    for (int i = 0; i < 2; ++i)
#pragma unroll
        for (int j = 0; j < 8; ++j)
#pragma unroll
            for (int c = 0; c < 4; ++c) sacc[i][j][c] = 0.f;

#pragma unroll
    for (int seg = 0; seg < 3; ++seg) {
        const unsigned short* Kbase = sKP + ((seg == 1) ? 8192 : 0);
#pragma unroll
        for (int kc = 0; kc < 2; ++kc) {
            bf16x8 bv[8];
#pragma unroll
            for (int tj = 0; tj < 8; ++tj)
                bv[tj] = *(const bf16x8*)&Kbase[KSWZ(tj * 16 + fr, kc * 32 + quad * 8)];
#pragma unroll
            for (int ti = 0; ti < 2; ++ti) {
                bf16x8 av = (seg == 2) ? ql[ti][kc] : qh[ti][kc];
#pragma unroll
                for (int tj = 0; tj < 8; ++tj)
                    sacc[ti][tj] = __builtin_amdgcn_mfma_f32_16x16x32_bf16(
                        av, bv[tj], sacc[ti][tj], 0, 0, 0);
            }
        }
    }
    __syncthreads();   // all waves done reading K before P overwrites it

    // ---- rel + exp -> P (bf16, swizzled [r][j]); row-sums ----
    const unsigned short* relbase = relbT + (((size_t)bh * NB + bi) * 512 + ct * 128) * 128;
    float lsum[2][4] = {{0.f, 0.f, 0.f, 0.f}, {0.f, 0.f, 0.f, 0.f}};
#pragma unroll
    for (int ti = 0; ti < 2; ++ti) {
        int mr = wave * 32 + ti * 16 + quad * 4;
#pragma unroll
        for (int tj = 0; tj < 8; ++tj) {
            int j = tj * 16 + fr;
            ushort4 rl = *(const ushort4*)&relbase[(size_t)j * 128 + mr];
            unsigned short rr[4] = {rl.x, rl.y, rl.z, rl.w};
#pragma unroll
            for (int reg = 0; reg < 4; ++reg) {
                int r = mr + reg;
                float p = __expf(sacc[ti][tj][reg] + bf2f(rr[reg]));
                unsigned short pb = f2bf(p);
                lsum[ti][reg] += bf2f(pb);     // l consistent with bf16 P
                sKP[PSWZ(r, j)] = pb;
            }
        }
    }
#pragma unroll
    for (int m2 = 1; m2 < 16; m2 <<= 1)
#pragma unroll
        for (int ti = 0; ti < 2; ++ti)
#pragma unroll
            for (int reg = 0; reg < 4; ++reg)
                lsum[ti][reg] += __shfl_xor(lsum[ti][reg], m2, 64);
    if (fr == 0) {
#pragma unroll
        for (int ti = 0; ti < 2; ++ti) {
            int mr = wave * 32 + ti * 16 + quad * 4;
#pragma unroll
            for (int reg = 0; reg < 4; ++reg)
                lp[mr + reg] = lsum[ti][reg];
        }
    }

    // ---- O^T = Vt x P^T  (each wave consumes only its own P rows) ----
    f32x4 oacc[4][2];
#pragma unroll
    for (int i = 0; i < 4; ++i)
#pragma unroll
        for (int j = 0; j < 2; ++j)
#pragma unroll
            for (int c = 0; c < 4; ++c) oacc[i][j][c] = 0.f;

#pragma unroll
    for (int kc = 0; kc < 4; ++kc) {
        bf16x8 pbv[2];
#pragma unroll
        for (int rt2 = 0; rt2 < 2; ++rt2) {
            int r = (wave * 2 + rt2) * 16 + fr;
            pbv[rt2] = *(const bf16x8*)&sKP[PSWZ(r, kc * 32 + quad * 8)];
        }
#pragma unroll
        for (int dt = 0; dt < 4; ++dt) {
            int aoff = (dt * 16 + fr) * VSTR + kc * 32 + quad * 8;
            bf16x8 avh = *(const bf16x8*)&sVh[aoff];
            bf16x8 avl = *(const bf16x8*)&sVl[aoff];
#pragma unroll
            for (int rt2 = 0; rt2 < 2; ++rt2) {
                oacc[dt][rt2] = __builtin_amdgcn_mfma_f32_16x16x32_bf16(
                    avh, pbv[rt2], oacc[dt][rt2], 0, 0, 0);
                oacc[dt][rt2] = __builtin_amdgcn_mfma_f32_16x16x32_bf16(
                    avl, pbv[rt2], oacc[dt][rt2], 0, 0, 0);
            }
        }
    }
#pragma unroll
    for (int dt = 0; dt < 4; ++dt)
#pragma unroll
        for (int rt2 = 0; rt2 < 2; ++rt2) {
            int r = (wave * 2 + rt2) * 16 + fr;
            int d = dt * 16 + quad * 4;
            float4 ov = make_float4(oacc[dt][rt2][0], oacc[dt][rt2][1],
                                    oacc[dt][rt2][2], oacc[dt][rt2][3]);
            *(float4*)(Op + (size_t)r * 64 + d) = ov;
        }
}

// ---------------------------------------------------------------------------
// Global-column contribution (cols 0..3) for bi>=2: RMW into slice 0.
// ---------------------------------------------------------------------------
__global__ __launch_bounds__(128) void attn_gcols(
    const float* __restrict__ qkv, const float* __restrict__ rkk,
    const float* __restrict__ drk, const float* __restrict__ cb,
    float* __restrict__ O_part, float* __restrict__ l_part)
{
    const int bi = blockIdx.x + 2, bh = blockIdx.y;
    const int b = bh >> 3, h = bh & 7;
    const int i = bi * 128 + threadIdx.x;
    float qc[64];
    {
        const float* qrow = qkv + (size_t)(b * NSEQ + i) * HD3 + h * 64;
#pragma unroll
        for (int d4 = 0; d4 < 16; ++d4) {
            float4 qv = *(const float4*)(qrow + d4 * 4);
            float4 cv = *(const float4*)(cb + h * 64 + d4 * 4);
            qc[4 * d4 + 0] = qv.x + cv.x;
            qc[4 * d4 + 1] = qv.y + cv.y;
            qc[4 * d4 + 2] = qv.z + cv.z;
            qc[4 * d4 + 3] = qv.w + cv.w;
        }
    }
    float O[64];
#pragma unroll
    for (int d = 0; d < 64; ++d) O[d] = 0.f;
    float l = 0.f;
    for (int j = 0; j < 4; ++j) {
        const float* krow = qkv + ((size_t)(b * NSEQ + j)) * HD3 + 512 + h * 64;
        int jj = j - i + (NSEQ - 1);
        const float* rrow = rkk + (size_t)jj * RKLD + h * 64;
        float s0 = 0, s1 = 0, s2 = 0, s3 = 0;
#pragma unroll
        for (int d4 = 0; d4 < 16; ++d4) {
            float4 kv = *(const float4*)(krow + d4 * 4);
            float4 rv = *(const float4*)(rrow + d4 * 4);
            s0 = fmaf(qc[4 * d4 + 0], kv.x + rv.x, s0);
            s1 = fmaf(qc[4 * d4 + 1], kv.y + rv.y, s1);
            s2 = fmaf(qc[4 * d4 + 2], kv.z + rv.z, s2);
            s3 = fmaf(qc[4 * d4 + 3], kv.w + rv.w, s3);
        }
        float p = __expf((s0 + s1) + (s2 + s3) + drk[h * RLEN + jj]);
        l += p;
        const float* vrow = krow + 512;
#pragma unroll
        for (int d4 = 0; d4 < 16; ++d4) {
            float4 vf = *(const float4*)(vrow + d4 * 4);
            O[4 * d4 + 0] = fmaf(p, vf.x, O[4 * d4 + 0]);
            O[4 * d4 + 1] = fmaf(p, vf.y, O[4 * d4 + 1]);
            O[4 * d4 + 2] = fmaf(p, vf.z, O[4 * d4 + 2]);
            O[4 * d4 + 3] = fmaf(p, vf.w, O[4 * d4 + 3]);
        }
    }
    float* Op = O_part + ((size_t)bh * NSEQ + i) * 64;   // slice 0
#pragma unroll
    for (int d4 = 0; d4 < 16; ++d4) {
        float4 cur = *(float4*)(Op + d4 * 4);
        cur.x += O[4 * d4 + 0]; cur.y += O[4 * d4 + 1];
        cur.z += O[4 * d4 + 2]; cur.w += O[4 * d4 + 3];
        *(float4*)(Op + d4 * 4) = cur;
    }
    l_part[(size_t)bh * NSEQ + i] += l;
}

// ---------------------------------------------------------------------------
// Global-ROW attention partials: grid (12 col-chunks, 64 bhi), 256 thr.
// ---------------------------------------------------------------------------
__global__ __launch_bounds__(256) void grows_part(
    const float* __restrict__ qkv, const float* __restrict__ rkk,
    const float* __restrict__ drk, const float* __restrict__ cb,
    float* __restrict__ g_O, float* __restrict__ g_l)
{
    __shared__ float qc_s[64];
    __shared__ float p_s[128];
    __shared__ float obuf[4][64];
    __shared__ float lred[2];
    const int chunk = blockIdx.x;        // 0..11
    const int bhi = blockIdx.y;          // 0..63
    const int i = bhi & 3, h = (bhi >> 2) & 7, b = bhi >> 5;
    const int t = threadIdx.x;
    const int c0 = chunk * 128;
    if (t < 64)
        qc_s[t] = qkv[(size_t)(b * NSEQ + i) * HD3 + h * 64 + t] + cb[h * 64 + t];
    __syncthreads();
    if (t < 128) {
        int j = c0 + t;
        const float* krow = qkv + (size_t)(b * NSEQ + j) * HD3 + 512 + h * 64;
        int jj = j - i + (NSEQ - 1);
        const float* rrow = rkk + (size_t)jj * RKLD + h * 64;
        float s0 = 0, s1 = 0, s2 = 0, s3 = 0;
#pragma unroll
        for (int d4 = 0; d4 < 16; ++d4) {
            float4 kv = *(const float4*)(krow + d4 * 4);
            float4 rv = *(const float4*)(rrow + d4 * 4);
            float4 qv = *(const float4*)(&qc_s[d4 * 4]);
            s0 = fmaf(qv.x, kv.x + rv.x, s0);
            s1 = fmaf(qv.y, kv.y + rv.y, s1);
            s2 = fmaf(qv.z, kv.z + rv.z, s2);
            s3 = fmaf(qv.w, kv.w + rv.w, s3);
        }
        float p = __expf((s0 + s1) + (s2 + s3) + drk[h * RLEN + jj]);
        p_s[t] = p;
        float ls = p;
#pragma unroll
        for (int off = 32; off > 0; off >>= 1)
            ls += __shfl_down(ls, off, 64);
        if ((t & 63) == 0) lred[t >> 6] = ls;
    }
    __syncthreads();
    {
        const int d = t & 63, g = t >> 6;
        float a0 = 0, a1 = 0;
        const float* vbase = qkv + (size_t)(b * NSEQ + c0 + g * 32) * HD3 + 1024 + h * 64 + d;
#pragma unroll
        for (int j2 = 0; j2 < 32; j2 += 2) {
            a0 = fmaf(p_s[g * 32 + j2],     vbase[(size_t)j2 * HD3],       a0);
            a1 = fmaf(p_s[g * 32 + j2 + 1], vbase[(size_t)(j2 + 1) * HD3], a1);
        }
        obuf[g][d] = a0 + a1;
    }
    __syncthreads();
    if (t < 64) {
        float o = (obuf[0][t] + obuf[1][t]) + (obuf[2][t] + obuf[3][t]);
        g_O[((size_t)chunk * 64 + bhi) * 64 + t] = o;
        if (t == 0) g_l[chunk * 64 + bhi] = lred[0] + lred[1];
    }
}

// ---------------------------------------------------------------------------
// Merge 3 ct-slices, normalize, emit ao as f16 (single-term out-proj).
// Rows i<4 (global rows) take their (O,l) from the 12 grows_part chunks.
// ---------------------------------------------------------------------------
__global__ __launch_bounds__(256) void norm_merge(
    const float* __restrict__ O_part, const float* __restrict__ l_part,
    const float* __restrict__ g_O, const float* __restrict__ g_l,
    _Float16* __restrict__ aoh)
{
    const int bh = blockIdx.y, b = bh >> 3, h = bh & 7;
    const int i = blockIdx.x * 16 + (threadIdx.x >> 4);
    const int d4 = threadIdx.x & 15;
    float ox = 0, oy = 0, oz = 0, ow = 0, l = 0;
    if (i < 4) {          // global row: sum the 12 column-chunk partials
        const int bhi = bh * 4 + i;
#pragma unroll
        for (int c = 0; c < 12; ++c) {
            const float* gp = g_O + ((size_t)c * 64 + bhi) * 64 + d4 * 4;
            ox += gp[0]; oy += gp[1]; oz += gp[2]; ow += gp[3];
            l += g_l[c * 64 + bhi];
        }
    } else {
#pragma unroll
        for (int s = 0; s < 3; ++s) {
            const float* Opp = O_part + (((size_t)s * 16 + bh) * NSEQ + i) * 64 + d4 * 4;
            float4 p = *(const float4*)Opp;
            ox += p.x; oy += p.y; oz += p.z; ow += p.w;
            l += l_part[((size_t)s * 16 + bh) * NSEQ + i];
        }
    }
    float inv = 1.f / l;
    union { _Float16 h[4]; ushort4 u; } cc;
    cc.h[0] = (_Float16)(ox * inv); cc.h[1] = (_Float16)(oy * inv);
    cc.h[2] = (_Float16)(oz * inv); cc.h[3] = (_Float16)(ow * inv);
    size_t o = ((size_t)(b * NSEQ + i)) * 512 + h * 64 + d4 * 4;
    *(ushort4*)(aoh + o) = cc.u;
}

// ---------------------------------------------------------------------------
extern "C" void kernel_launch(void* const* d_in, const int* in_sizes, int n_in,
                              void* d_out, int out_size, void* d_ws, size_t ws_size,
                              hipStream_t stream)
{
    const float* x    = (const float*)d_in[0];
    const float* Wq   = (const float*)d_in[1];
    const float* Wk   = (const float*)d_in[2];
    const float* Wv   = (const float*)d_in[3];
    const float* Wrel = (const float*)d_in[4];
    const float* cb   = (const float*)d_in[5];
    const float* rb   = (const float*)d_in[6];
    const float* Wo   = (const float*)d_in[7];
    const float* bo   = (const float*)d_in[8];
    const float* pe   = (const float*)d_in[9];
    float* out = (float*)d_out;

    float* ws = (float*)d_ws;
    float* qkv   = ws;                                   // [3072][1536] f32
    float* rkbuf = ws + 4718592;                         // [3071][512] f32
    float* drk   = ws + 6291456;                         // [8][3071] f32
    _Float16* aoh = (_Float16*)(ws + 6316032);           // [3072][512] f16
    _Float16* woh = (_Float16*)(ws + 7888896);           // WoT [1536][512] f16
    float* R = ws + 8675328;                             // aliased region
    unsigned short* relbT = (unsigned short*)R;              // [16][12][512][128] bf16
    _Float16* xh  = (_Float16*)R;                            // dead before relbT written
    _Float16* wqh = (_Float16*)(R + 4718592);                // WqkvT [1536][1536] f16
    float* g_O = R + 6291456;                            // [12][64][64] f32 (after relbT)
    float* g_l = R + 6340608;                            // [12][64] f32
    float* O_part = ws + 15753216;                       // [3][16][1536][64] f32
    float* l_part = ws + 20471808;                       // [3][16][1536] f32

    dim3 blk(256);
    splitf16<<<4608, blk, 0, stream>>>(x, xh, 1179648);
    wsplit_qkv16<<<dim3(8, 24, 3), blk, 0, stream>>>(Wq, Wk, Wv, wqh);
    wsplit_t16<<<dim3(24, 8), blk, 0, stream>>>(Wo, woh, 512, 1536, 0, 512, 1.f);
    gemm_f16k<<<dim3(24, 48), blk, 0, stream>>>(xh, wqh, nullptr, qkv,
                                                3072, 1536, 1536);
    gemm_f32<<<dim3(8, 48), blk, 0, stream>>>(pe, Wrel, nullptr, rkbuf, 3071, 512, 192, 1.f);
    drk_kernel<<<96, blk, 0, stream>>>(rkbuf, cb, rb, drk);
    relb_mfma<<<dim3(4, 12, 16), blk, 0, stream>>>(qkv, rkbuf, rb, relbT);
    attn_mfma<<<dim3(3, 12, 16), blk, 0, stream>>>(qkv, relbT, cb, O_part, l_part);
    attn_gcols<<<dim3(10, 16), dim3(128), 0, stream>>>(qkv, rkbuf, drk, cb, O_part, l_part);
    grows_part<<<dim3(12, 64), blk, 0, stream>>>(qkv, rkbuf, drk, cb, g_O, g_l);
    norm_merge<<<dim3(96, 16), blk, 0, stream>>>(O_part, l_part, g_O, g_l, aoh);
    gemm_f16k<<<dim3(24, 48), blk, 0, stream>>>(aoh, woh, bo, out,
                                                3072, 1536, 512);
}

// Round 4
// 268.213 us; speedup vs baseline: 1.1381x; 1.0131x over previous
//
#include <hip/hip_runtime.h>
#include <math.h>

#define NSEQ 1536
#define HD3  1536      // fused qkv row stride
#define RKLD 512       // rel_k row stride
#define RLEN 3071
#define NB   12

typedef __attribute__((ext_vector_type(8))) short bf16x8;
typedef __attribute__((ext_vector_type(4))) float f32x4;
typedef _Float16 f16x8 __attribute__((ext_vector_type(8)));
typedef _Float16 f16x4 __attribute__((ext_vector_type(4)));

__device__ __forceinline__ unsigned short f2bf(float f) {
    union { float f; unsigned u; } v; v.f = f;
    unsigned r = v.u + 0x7fffu + ((v.u >> 16) & 1u);
    return (unsigned short)(r >> 16);
}
__device__ __forceinline__ float bf2f(unsigned short s) {
    union { unsigned u; float f; } v; v.u = ((unsigned)s) << 16;
    return v.f;
}
__device__ __forceinline__ void cp16(const void* g, void* l) {
    __builtin_amdgcn_global_load_lds(
        (const __attribute__((address_space(1))) void*)g,
        (__attribute__((address_space(3))) void*)l, 16, 0, 0);
}

// LDS swizzles: keep 8-elem chunks contiguous; XOR chunk id with row bits to
// break power-of-2 stride bank conflicts.
#define KSWZ(row, d) ((row) * 64 + (((((d) >> 3) ^ ((row) & 7))) << 3) + ((d) & 7))
#define PSWZ(r, j)   ((r) * 128 + (((((j) >> 3) ^ ((r) & 15))) << 3) + ((j) & 7))
#define VSTR 136     // Vt row stride in elems (272B: 16B-aligned, non-pow2)

// ---------------------------------------------------------------------------
// fp32 -> f16 (single-term GEMM input)
// ---------------------------------------------------------------------------
__global__ __launch_bounds__(256) void splitf16(
    const float* __restrict__ X, _Float16* __restrict__ H, int n4)
{
    int i = blockIdx.x * 256 + threadIdx.x;
    if (i >= n4) return;
    float4 v = ((const float4*)X)[i];
    union { _Float16 h[4]; ushort4 u; } c;
    c.h[0] = (_Float16)v.x; c.h[1] = (_Float16)v.y;
    c.h[2] = (_Float16)v.z; c.h[3] = (_Float16)v.w;
    ((ushort4*)H)[i] = c.u;
}

// ---------------------------------------------------------------------------
// Weight transpose (generic): W[K][N] f32 -> T[n_off+N][ldt] f16
// ---------------------------------------------------------------------------
__device__ __forceinline__ void wsplit_body16(
    const float* __restrict__ W, _Float16* __restrict__ T,
    int K, int N, int n_off, int ldt, float scale, int bx, int by)
{
    __shared__ float tile[64][65];
    const int k0 = by * 64, n0 = bx * 64;
    const int t = threadIdx.x;
    const int rr = t >> 4, c4 = (t & 15) * 4;
#pragma unroll
    for (int p = 0; p < 4; ++p) {
        int r = p * 16 + rr;
        float4 v = *(const float4*)(W + (size_t)(k0 + r) * N + n0 + c4);
        tile[r][c4 + 0] = v.x; tile[r][c4 + 1] = v.y;
        tile[r][c4 + 2] = v.z; tile[r][c4 + 3] = v.w;
    }
    __syncthreads();
#pragma unroll
    for (int p = 0; p < 4; ++p) {
        int n = p * 16 + rr;
        union { _Float16 h[4]; ushort4 u; } cc;
        cc.h[0] = (_Float16)(tile[c4 + 0][n] * scale);
        cc.h[1] = (_Float16)(tile[c4 + 1][n] * scale);
        cc.h[2] = (_Float16)(tile[c4 + 2][n] * scale);
        cc.h[3] = (_Float16)(tile[c4 + 3][n] * scale);
        size_t o = (size_t)(n_off + n0 + n) * ldt + k0 + c4;
        *(ushort4*)(T + o) = cc.u;
    }
}

__global__ __launch_bounds__(256) void wsplit_qkv16(
    const float* __restrict__ Wq, const float* __restrict__ Wk,
    const float* __restrict__ Wv, _Float16* __restrict__ T)
{
    const int z = blockIdx.z;
    const float* W = (z == 0) ? Wq : (z == 1) ? Wk : Wv;
    wsplit_body16(W, T, 1536, 512, z * 512, 1536, (z == 0) ? 0.125f : 1.f,
                  blockIdx.x, blockIdx.y);
}

__global__ __launch_bounds__(256) void wsplit_t16(
    const float* __restrict__ W, _Float16* __restrict__ T,
    int K, int N, int n_off, int ldt, float scale)
{
    wsplit_body16(W, T, K, N, n_off, ldt, scale, blockIdx.x, blockIdx.y);
}

// ---------------------------------------------------------------------------
// Single-term f16 MFMA GEMM, 64x64 tile, BK=64: C = A·B^T (+bias).
// Grid 1152 (4.5 blocks/CU, 90% balance). 2-buffer single-barrier; 32KB LDS;
// KSWZ; XCD swizzle. (R2: validated, absmax improved vs split-bf16.)
// ---------------------------------------------------------------------------
__global__ __launch_bounds__(256) void gemm_f16k(
    const _Float16* __restrict__ A,   // [M][K] f16
    const _Float16* __restrict__ B,   // [N][K] f16 (pre-transposed weight)
    const float* __restrict__ bias, float* __restrict__ C,
    int M, int N, int K)
{
    __shared__ _Float16 sA[2][4096];    // [buf][64*64]
    __shared__ _Float16 sB[2][4096];
    const int t = threadIdx.x;
    const int wave = t >> 6, lane = t & 63;
    // XCD-aware bijective swizzle (nwg % 8 == 0 for all launches here)
    const int nwg = gridDim.x * gridDim.y;
    const int lin = blockIdx.y * gridDim.x + blockIdx.x;
    const int swz = (lin & 7) * (nwg >> 3) + (lin >> 3);
    const int bx = swz % gridDim.x, by = swz / gridDim.x;
    const int m0 = by * 64, n0 = bx * 64;
    const int wm = (wave >> 1) * 32, wn = (wave & 1) * 32;
    const int fr = lane & 15, quad = lane >> 4;

    f32x4 acc[2][2];
#pragma unroll
    for (int i = 0; i < 2; ++i)
#pragma unroll
        for (int j = 0; j < 2; ++j)
#pragma unroll
            for (int c = 0; c < 4; ++c) acc[i][j][c] = 0.f;

    const int nsteps = K >> 6;

// 2 cp16 per array per thread per stage; LDS dest linear (wave base + lane*16B),
// global source pre-swizzled so LDS slot (row, c) holds chunk c^(row&7) (KSWZ).
#define STAGE(k0, buf)                                                        \
    {                                                                         \
        _Pragma("unroll")                                                     \
        for (int it = 0; it < 2; ++it) {                                      \
            int cidx = it * 256 + t;                                          \
            int row = cidx >> 3, slot = cidx & 7;                             \
            int gch = slot ^ (row & 7);                                       \
            size_t goA = (size_t)(m0 + row) * K + (k0) + gch * 8;             \
            size_t goB = (size_t)(n0 + row) * K + (k0) + gch * 8;             \
            cp16(A + goA, &sA[buf][it * 2048 + wave * 512]);                  \
            cp16(B + goB, &sB[buf][it * 2048 + wave * 512]);                  \
        }                                                                     \
    }

    STAGE(0, 0);
    for (int s = 0; s < nsteps; ++s) {
        const int buf = s & 1;
        __syncthreads();
        if (s + 1 < nsteps) STAGE((s + 1) * 64, buf ^ 1);

        f16x8 fa[2][2], fb[2][2];
#pragma unroll
        for (int ti = 0; ti < 2; ++ti)
#pragma unroll
            for (int kc = 0; kc < 2; ++kc) {
                fa[ti][kc] = *(const f16x8*)&sA[buf][KSWZ(wm + ti * 16 + fr,
                                                          kc * 32 + quad * 8)];
                fb[ti][kc] = *(const f16x8*)&sB[buf][KSWZ(wn + ti * 16 + fr,
                                                          kc * 32 + quad * 8)];
            }
#pragma unroll
        for (int ti = 0; ti < 2; ++ti)
#pragma unroll
            for (int tj = 0; tj < 2; ++tj)
#pragma unroll
                for (int kc = 0; kc < 2; ++kc)
                    acc[ti][tj] = __builtin_amdgcn_mfma_f32_16x16x32_f16(
                        fa[ti][kc], fb[tj][kc], acc[ti][tj], 0, 0, 0);
    }
#undef STAGE

#pragma unroll
    for (int ti = 0; ti < 2; ++ti) {
        int rowb = m0 + wm + ti * 16 + quad * 4;
#pragma unroll
        for (int tj = 0; tj < 2; ++tj) {
            int col = n0 + wn + tj * 16 + fr;
            float bb = bias ? bias[col] : 0.f;
#pragma unroll
            for (int j2 = 0; j2 < 4; ++j2)
                C[(size_t)(rowb + j2) * N + col] = acc[ti][tj][j2] + bb;
        }
    }
}

// ---------------------------------------------------------------------------
// Generic fp32 GEMM (rel_k = pos_embed @ Wrel; K=192), 64x64 tiles.
// ---------------------------------------------------------------------------
__global__ __launch_bounds__(256) void gemm_f32(
    const float* __restrict__ A, const float* __restrict__ B,
    const float* __restrict__ bias, float* __restrict__ C,
    int M, int N, int K, float alpha)
{
    __shared__ float As_[16][68];
    __shared__ float Bs_[16][68];
    const int t = threadIdx.x;
    const int m0 = blockIdx.y * 64;
    const int n0 = blockIdx.x * 64;
    const int tm = t >> 4, tn = t & 15;
    float acc[4][4];
#pragma unroll
    for (int i = 0; i < 4; ++i)
#pragma unroll
        for (int j = 0; j < 4; ++j) acc[i][j] = 0.f;

    for (int k0 = 0; k0 < K; k0 += 16) {
        {
            int row = t >> 2;           // 0..63
            int kk  = (t & 3) * 4;
            int gm  = m0 + row;
            float4 av = make_float4(0.f, 0.f, 0.f, 0.f);
            if (gm < M) av = *(const float4*)(A + (size_t)gm * K + k0 + kk);
            As_[kk + 0][row] = av.x; As_[kk + 1][row] = av.y;
            As_[kk + 2][row] = av.z; As_[kk + 3][row] = av.w;
        }
        {
            int kk = t >> 4;            // 0..15
            int nn = (t & 15) * 4;
            float4 bv = *(const float4*)(B + (size_t)(k0 + kk) * N + n0 + nn);
            *(float4*)&Bs_[kk][nn] = bv;
        }
        __syncthreads();
#pragma unroll
        for (int kk = 0; kk < 16; ++kk) {
            float a[4], bb[4];
            *(float4*)&a[0]  = *(const float4*)&As_[kk][tm * 4];
            *(float4*)&bb[0] = *(const float4*)&Bs_[kk][tn * 4];
#pragma unroll
            for (int i = 0; i < 4; ++i)
#pragma unroll
                for (int j = 0; j < 4; ++j)
                    acc[i][j] = fmaf(a[i], bb[j], acc[i][j]);
        }
        __syncthreads();
    }
#pragma unroll
    for (int i = 0; i < 4; ++i) {
        int gm = m0 + tm * 4 + i;
        if (gm < M) {
            float* crow = C + (size_t)gm * N + n0 + tn * 4;
#pragma unroll
            for (int j = 0; j < 4; ++j) {
                float vv = acc[i][j] * alpha;
                if (bias) vv += bias[n0 + tn * 4 + j];
                crow[j] = vv;
            }
        }
    }
}

// ---------------------------------------------------------------------------
// drk[h][jj] = sum_d (rpb[h,d]-rcb[h,d]) * rk[jj, h*64+d]
// ---------------------------------------------------------------------------
__global__ __launch_bounds__(256) void drk_kernel(
    const float* __restrict__ rkk, const float* __restrict__ cb,
    const float* __restrict__ rb, float* __restrict__ drk)
{
    int idx = blockIdx.x * 256 + threadIdx.x;
    if (idx >= 8 * RLEN) return;
    int jj = idx >> 3, h = idx & 7;
    const float* rrow = rkk + (size_t)jj * RKLD + h * 64;
    float s0 = 0, s1 = 0, s2 = 0, s3 = 0;
#pragma unroll
    for (int d4 = 0; d4 < 16; ++d4) {
        float4 rv = *(const float4*)(rrow + d4 * 4);
        float dx = rb[h * 64 + d4 * 4 + 0] - cb[h * 64 + d4 * 4 + 0];
        float dy = rb[h * 64 + d4 * 4 + 1] - cb[h * 64 + d4 * 4 + 1];
        float dz = rb[h * 64 + d4 * 4 + 2] - cb[h * 64 + d4 * 4 + 2];
        float dw = rb[h * 64 + d4 * 4 + 3] - cb[h * 64 + d4 * 4 + 3];
        s0 = fmaf(dx, rv.x, s0); s1 = fmaf(dy, rv.y, s1);
        s2 = fmaf(dz, rv.z, s2); s3 = fmaf(dw, rv.w, s3);
    }
    drk[h * RLEN + jj] = (s0 + s1) + (s2 + s3);
}

// ---------------------------------------------------------------------------
// Banded rel logits via f16 MFMA (single-term; logit err ~1e-3, rel logits
// sigma~2.3 so f16 range safe), stored SHIFTED+TRANSPOSED f16:
// relbT[bh][bi][jl][r], jl = ccg-127+r.
// ---------------------------------------------------------------------------
__global__ __launch_bounds__(256) void relb_mfma(
    const float* __restrict__ qkv, const float* __restrict__ rkk,
    const float* __restrict__ rb, _Float16* __restrict__ relbT)
{
    __shared__ _Float16 sR[8192];   // 128 band rows x 64 d
    const int ct = blockIdx.x, bi = blockIdx.y, bh = blockIdx.z;
    const int b = bh >> 3, h = bh & 7;
    const int i0 = bi * 128;
    const int c0 = (bi == 0) ? 0 : (bi - 1) * 128;
    const int jjbase = c0 - i0 - 127 + (NSEQ - 1) + ct * 128;  // in [1280,1920)
    const int t = threadIdx.x;
    const int wave = t >> 6, lane = t & 63;
    const int fr = lane & 15, quad = lane >> 4;

    // ---- stage rk band (f16, swizzled [cc][64]) ----
#pragma unroll
    for (int it = 0; it < 8; ++it) {
        int lin = it * 256 + t;            // 0..2047
        int row = lin >> 4, d4 = (lin & 15) * 4;
        const float* rp = rkk + (size_t)(jjbase + row) * RKLD + h * 64 + d4;
        float4 v = *(const float4*)rp;
        union { _Float16 h[4]; ushort4 u; } cc;
        cc.h[0] = (_Float16)v.x; cc.h[1] = (_Float16)v.y;
        cc.h[2] = (_Float16)v.z; cc.h[3] = (_Float16)v.w;
        *(ushort4*)&sR[KSWZ(row, d4)] = cc.u;
    }
    // ---- Q + rel-pos-bias fragments (f16) ----
    f16x8 qf[2][2];
    {
        const float* Qg = qkv + ((size_t)(b * NSEQ + i0)) * HD3 + h * 64;
#pragma unroll
        for (int ti = 0; ti < 2; ++ti)
#pragma unroll
            for (int kc = 0; kc < 2; ++kc) {
                int m = wave * 32 + ti * 16 + fr;
                int k8 = kc * 32 + quad * 8;
                const float* qp = Qg + (size_t)m * HD3 + k8;
                const float* cp = rb + h * 64 + k8;
                float4 qa = *(const float4*)qp,  qb = *(const float4*)(qp + 4);
                float4 ca = *(const float4*)cp,  c2 = *(const float4*)(cp + 4);
                _Float16 hx[8] = {
                    (_Float16)(qa.x + ca.x), (_Float16)(qa.y + ca.y),
                    (_Float16)(qa.z + ca.z), (_Float16)(qa.w + ca.w),
                    (_Float16)(qb.x + c2.x), (_Float16)(qb.y + c2.y),
                    (_Float16)(qb.z + c2.z), (_Float16)(qb.w + c2.w)};
                qf[ti][kc] = *(f16x8*)hx;
            }
    }
    __syncthreads();

    // ---- S = (Q+rpb) · rk^T ----
    f32x4 sacc[2][8];
#pragma unroll
    for (int i = 0; i < 2; ++i)
#pragma unroll
        for (int j = 0; j < 8; ++j)
#pragma unroll
            for (int c = 0; c < 4; ++c) sacc[i][j][c] = 0.f;

#pragma unroll
    for (int kc = 0; kc < 2; ++kc) {
        f16x8 bv[8];
#pragma unroll
        for (int tj = 0; tj < 8; ++tj)
            bv[tj] = *(const f16x8*)&sR[KSWZ(tj * 16 + fr, kc * 32 + quad * 8)];
#pragma unroll
        for (int ti = 0; ti < 2; ++ti)
#pragma unroll
            for (int tj = 0; tj < 8; ++tj)
                sacc[ti][tj] = __builtin_amdgcn_mfma_f32_16x16x32_f16(
                    qf[ti][kc], bv[tj], sacc[ti][tj], 0, 0, 0);
    }

    // ---- shifted scatter-store to relbT ----
    size_t bb_ = ((size_t)bh * NB + bi) * 512;
#pragma unroll
    for (int ti = 0; ti < 2; ++ti) {
        int mr = wave * 32 + ti * 16 + quad * 4;
#pragma unroll
        for (int tj = 0; tj < 8; ++tj) {
            int ccg = ct * 128 + tj * 16 + fr;
#pragma unroll
            for (int reg = 0; reg < 4; ++reg) {
                int r = mr + reg;
                int jl = ccg - 127 + r;            // < 512 always
                if (jl >= 0)
                    relbT[(bb_ + jl) * 128 + r] = (_Float16)sacc[ti][tj][reg];
            }
        }
    }
}

// ---------------------------------------------------------------------------
// MFMA flash attention (local window). WG per (ct, bi, bh), 4 waves.
// QK^T in f16 (f32 accum, overflow-free). P MUST be bf16: softmax is
// UNNORMALIZED (no row-max subtraction) so p=exp(s) reaches ~1e13 — f16
// overflows at 65504 (R3 NaN). V staged bf16-hi single-term; PV bf16 MFMA.
// ---------------------------------------------------------------------------
__global__ __launch_bounds__(256) void attn_mfma(
    const float* __restrict__ qkv, const _Float16* __restrict__ relbT,
    const float* __restrict__ cb, float* __restrict__ O_part,
    float* __restrict__ l_part)
{
    __shared__ unsigned short sKP[16384];   // K f16 [0:8192] -> P bf16 (PSWZ, full)
    __shared__ unsigned short sVt[64 * VSTR];  // V^T bf16-hi [d][VSTR]
    const int ct = blockIdx.x, bi = blockIdx.y, bh = blockIdx.z;
    const int b = bh >> 3, h = bh & 7;
    const int i0 = bi * 128;
    const int c0 = (bi == 0) ? 0 : (bi - 1) * 128;
    const int c1 = (bi == NB - 1) ? NSEQ : (bi + 2) * 128;
    const int ctile = c0 + ct * 128;
    const int t = threadIdx.x;
    const int wave = t >> 6, lane = t & 63;
    const int fr = lane & 15, quad = lane >> 4;

    float* Op = O_part + (((size_t)ct * 16 + bh) * NSEQ + i0) * 64;
    float* lp = l_part + ((size_t)ct * 16 + bh) * NSEQ + i0;

    if (ctile >= c1) {      // inactive edge tile: zero slice
        for (int k2 = t; k2 < 8192; k2 += 256) Op[k2] = 0.f;
        if (t < 128) lp[t] = 0.f;
        return;
    }

    // ---- stage K (f16 bits, swizzled [j][64]) ----
    {
        const float* Kg = qkv + ((size_t)(b * NSEQ + ctile)) * HD3 + 512 + h * 64;
#pragma unroll
        for (int it = 0; it < 8; ++it) {
            int lin = it * 256 + t;            // 0..2047
            int row = lin >> 4, d4 = (lin & 15) * 4;
            float4 v = *(const float4*)(Kg + (size_t)row * HD3 + d4);
            union { _Float16 h[4]; ushort4 u; } cc;
            cc.h[0] = (_Float16)v.x; cc.h[1] = (_Float16)v.y;
            cc.h[2] = (_Float16)v.z; cc.h[3] = (_Float16)v.w;
            *(ushort4*)&sKP[KSWZ(row, d4)] = cc.u;
        }
    }
    // ---- stage V transposed (bf16-hi, [d][VSTR]) ----
    {
        const float* Vg = qkv + ((size_t)(b * NSEQ + ctile)) * HD3 + 1024 + h * 64;
#pragma unroll
        for (int it = 0; it < 2; ++it) {
            int lin = it * 256 + t;            // 0..511
            int r4 = (lin >> 4) * 4, d4 = (lin & 15) * 4;
            float4 v0 = *(const float4*)(Vg + (size_t)(r4 + 0) * HD3 + d4);
            float4 v1 = *(const float4*)(Vg + (size_t)(r4 + 1) * HD3 + d4);
            float4 v2 = *(const float4*)(Vg + (size_t)(r4 + 2) * HD3 + d4);
            float4 v3 = *(const float4*)(Vg + (size_t)(r4 + 3) * HD3 + d4);
            const float* p0 = (const float*)&v0;
            const float* p1 = (const float*)&v1;
            const float* p2 = (const float*)&v2;
            const float* p3 = (const float*)&v3;
#pragma unroll
            for (int dd = 0; dd < 4; ++dd) {
                ushort4 hh;
                hh.x = f2bf(p0[dd]); hh.y = f2bf(p1[dd]);
                hh.z = f2bf(p2[dd]); hh.w = f2bf(p3[dd]);
                *(ushort4*)&sVt[(d4 + dd) * VSTR + r4] = hh;
            }
        }
    }
    // ---- Q fragments in registers (q + content bias, f16) ----
    f16x8 qf[2][2];
    {
        const float* Qg = qkv + ((size_t)(b * NSEQ + i0)) * HD3 + h * 64;
#pragma unroll
        for (int ti = 0; ti < 2; ++ti)
#pragma unroll
            for (int kc = 0; kc < 2; ++kc) {
                int m = wave * 32 + ti * 16 + fr;
                int k8 = kc * 32 + quad * 8;
                const float* qp = Qg + (size_t)m * HD3 + k8;
                const float* cp = cb + h * 64 + k8;
                float4 qa = *(const float4*)qp,  qb = *(const float4*)(qp + 4);
                float4 ca = *(const float4*)cp,  c2 = *(const float4*)(cp + 4);
                _Float16 hx[8] = {
                    (_Float16)(qa.x + ca.x), (_Float16)(qa.y + ca.y),
                    (_Float16)(qa.z + ca.z), (_Float16)(qa.w + ca.w),
                    (_Float16)(qb.x + c2.x), (_Float16)(qb.y + c2.y),
                    (_Float16)(qb.z + c2.z), (_Float16)(qb.w + c2.w)};
                qf[ti][kc] = *(f16x8*)hx;
            }
    }
    __syncthreads();

    // ---- S = Q K^T (f16 MFMA, f32 accum) ----
    f32x4 sacc[2][8];
#pragma unroll
    for (int i = 0; i < 2; ++i)
#pragma unroll
        for (int j = 0; j < 8; ++j)
#pragma unroll
            for (int c = 0; c < 4; ++c) sacc[i][j][c] = 0.f;

#pragma unroll
    for (int kc = 0; kc < 2; ++kc) {
        f16x8 bv[8];
#pragma unroll
        for (int tj = 0; tj < 8; ++tj)
            bv[tj] = *(const f16x8*)&sKP[KSWZ(tj * 16 + fr, kc * 32 + quad * 8)];
#pragma unroll
        for (int ti = 0; ti < 2; ++ti)
#pragma unroll
            for (int tj = 0; tj < 8; ++tj)
                sacc[ti][tj] = __builtin_amdgcn_mfma_f32_16x16x32_f16(
                    qf[ti][kc], bv[tj], sacc[ti][tj], 0, 0, 0);
    }
    __syncthreads();   // all waves done reading K before P overwrites it

    // ---- rel + exp -> P (bf16, swizzled [r][j]); row-sums ----
    const _Float16* relbase = relbT + (((size_t)bh * NB + bi) * 512 + ct * 128) * 128;
    float lsum[2][4] = {{0.f, 0.f, 0.f, 0.f}, {0.f, 0.f, 0.f, 0.f}};
#pragma unroll
    for (int ti = 0; ti < 2; ++ti) {
        int mr = wave * 32 + ti * 16 + quad * 4;
#pragma unroll
        for (int tj = 0; tj < 8; ++tj) {
            int j = tj * 16 + fr;
            f16x4 rl = *(const f16x4*)&relbase[(size_t)j * 128 + mr];
#pragma unroll
            for (int reg = 0; reg < 4; ++reg) {
                int r = mr + reg;
                float p = __expf(sacc[ti][tj][reg] + (float)rl[reg]);
                unsigned short pb = f2bf(p);
                lsum[ti][reg] += bf2f(pb);     // l consistent with bf16 P
                sKP[PSWZ(r, j)] = pb;
            }
        }
    }
#pragma unroll
    for (int m2 = 1; m2 < 16; m2 <<= 1)
#pragma unroll
        for (int ti = 0; ti < 2; ++ti)
#pragma unroll
            for (int reg = 0; reg < 4; ++reg)
                lsum[ti][reg] += __shfl_xor(lsum[ti][reg], m2, 64);
    if (fr == 0) {
#pragma unroll
        for (int ti = 0; ti < 2; ++ti) {
            int mr = wave * 32 + ti * 16 + quad * 4;
#pragma unroll
            for (int reg = 0; reg < 4; ++reg)
                lp[mr + reg] = lsum[ti][reg];
        }
    }

    // ---- O^T = Vt x P^T (bf16 MFMA; each wave consumes only its own P rows) ----
    f32x4 oacc[4][2];
#pragma unroll
    for (int i = 0; i < 4; ++i)
#pragma unroll
        for (int j = 0; j < 2; ++j)
#pragma unroll
            for (int c = 0; c < 4; ++c) oacc[i][j][c] = 0.f;

#pragma unroll
    for (int kc = 0; kc < 4; ++kc) {
        bf16x8 pbv[2];
#pragma unroll
        for (int rt2 = 0; rt2 < 2; ++rt2) {
            int r = (wave * 2 + rt2) * 16 + fr;
            pbv[rt2] = *(const bf16x8*)&sKP[PSWZ(r, kc * 32 + quad * 8)];
        }
#pragma unroll
        for (int dt = 0; dt < 4; ++dt) {
            bf16x8 av = *(const bf16x8*)&sVt[(dt * 16 + fr) * VSTR + kc * 32 + quad * 8];
#pragma unroll
            for (int rt2 = 0; rt2 < 2; ++rt2)
                oacc[dt][rt2] = __builtin_amdgcn_mfma_f32_16x16x32_bf16(
                    av, pbv[rt2], oacc[dt][rt2], 0, 0, 0);
        }
    }
#pragma unroll
    for (int dt = 0; dt < 4; ++dt)
#pragma unroll
        for (int rt2 = 0; rt2 < 2; ++rt2) {
            int r = (wave * 2 + rt2) * 16 + fr;
            int d = dt * 16 + quad * 4;
            float4 ov = make_float4(oacc[dt][rt2][0], oacc[dt][rt2][1],
                                    oacc[dt][rt2][2], oacc[dt][rt2][3]);
            *(float4*)(Op + (size_t)r * 64 + d) = ov;
        }
}

// ---------------------------------------------------------------------------
// Global-column contribution (cols 0..3) for bi>=2: RMW into slice 0.
// ---------------------------------------------------------------------------
__global__ __launch_bounds__(128) void attn_gcols(
    const float* __restrict__ qkv, const float* __restrict__ rkk,
    const float* __restrict__ drk, const float* __restrict__ cb,
    float* __restrict__ O_part, float* __restrict__ l_part)
{
    const int bi = blockIdx.x + 2, bh = blockIdx.y;
    const int b = bh >> 3, h = bh & 7;
    const int i = bi * 128 + threadIdx.x;
    float qc[64];
    {
        const float* qrow = qkv + (size_t)(b * NSEQ + i) * HD3 + h * 64;
#pragma unroll
        for (int d4 = 0; d4 < 16; ++d4) {
            float4 qv = *(const float4*)(qrow + d4 * 4);
            float4 cv = *(const float4*)(cb + h * 64 + d4 * 4);
            qc[4 * d4 + 0] = qv.x + cv.x;
            qc[4 * d4 + 1] = qv.y + cv.y;
            qc[4 * d4 + 2] = qv.z + cv.z;
            qc[4 * d4 + 3] = qv.w + cv.w;
        }
    }
    float O[64];
#pragma unroll
    for (int d = 0; d < 64; ++d) O[d] = 0.f;
    float l = 0.f;
    for (int j = 0; j < 4; ++j) {
        const float* krow = qkv + ((size_t)(b * NSEQ + j)) * HD3 + 512 + h * 64;
        int jj = j - i + (NSEQ - 1);
        const float* rrow = rkk + (size_t)jj * RKLD + h * 64;
        float s0 = 0, s1 = 0, s2 = 0, s3 = 0;
#pragma unroll
        for (int d4 = 0; d4 < 16; ++d4) {
            float4 kv = *(const float4*)(krow + d4 * 4);
            float4 rv = *(const float4*)(rrow + d4 * 4);
            s0 = fmaf(qc[4 * d4 + 0], kv.x + rv.x, s0);
            s1 = fmaf(qc[4 * d4 + 1], kv.y + rv.y, s1);
            s2 = fmaf(qc[4 * d4 + 2], kv.z + rv.z, s2);
            s3 = fmaf(qc[4 * d4 + 3], kv.w + rv.w, s3);
        }
        float p = __expf((s0 + s1) + (s2 + s3) + drk[h * RLEN + jj]);
        l += p;
        const float* vrow = krow + 512;
#pragma unroll
        for (int d4 = 0; d4 < 16; ++d4) {
            float4 vf = *(const float4*)(vrow + d4 * 4);
            O[4 * d4 + 0] = fmaf(p, vf.x, O[4 * d4 + 0]);
            O[4 * d4 + 1] = fmaf(p, vf.y, O[4 * d4 + 1]);
            O[4 * d4 + 2] = fmaf(p, vf.z, O[4 * d4 + 2]);
            O[4 * d4 + 3] = fmaf(p, vf.w, O[4 * d4 + 3]);
        }
    }
    float* Op = O_part + ((size_t)bh * NSEQ + i) * 64;   // slice 0
#pragma unroll
    for (int d4 = 0; d4 < 16; ++d4) {
        float4 cur = *(float4*)(Op + d4 * 4);
        cur.x += O[4 * d4 + 0]; cur.y += O[4 * d4 + 1];
        cur.z += O[4 * d4 + 2]; cur.w += O[4 * d4 + 3];
        *(float4*)(Op + d4 * 4) = cur;
    }
    l_part[(size_t)bh * NSEQ + i] += l;
}

// ---------------------------------------------------------------------------
// Global-ROW attention partials: grid (12 col-chunks, 64 bhi), 256 thr.
// ---------------------------------------------------------------------------
__global__ __launch_bounds__(256) void grows_part(
    const float* __restrict__ qkv, const float* __restrict__ rkk,
    const float* __restrict__ drk, const float* __restrict__ cb,
    float* __restrict__ g_O, float* __restrict__ g_l)
{
    __shared__ float qc_s[64];
    __shared__ float p_s[128];
    __shared__ float obuf[4][64];
    __shared__ float lred[2];
    const int chunk = blockIdx.x;        // 0..11
    const int bhi = blockIdx.y;          // 0..63
    const int i = bhi & 3, h = (bhi >> 2) & 7, b = bhi >> 5;
    const int t = threadIdx.x;
    const int c0 = chunk * 128;
    if (t < 64)
        qc_s[t] = qkv[(size_t)(b * NSEQ + i) * HD3 + h * 64 + t] + cb[h * 64 + t];
    __syncthreads();
    if (t < 128) {
        int j = c0 + t;
        const float* krow = qkv + (size_t)(b * NSEQ + j) * HD3 + 512 + h * 64;
        int jj = j - i + (NSEQ - 1);
        const float* rrow = rkk + (size_t)jj * RKLD + h * 64;
        float s0 = 0, s1 = 0, s2 = 0, s3 = 0;
#pragma unroll
        for (int d4 = 0; d4 < 16; ++d4) {
            float4 kv = *(const float4*)(krow + d4 * 4);
            float4 rv = *(const float4*)(rrow + d4 * 4);
            float4 qv = *(const float4*)(&qc_s[d4 * 4]);
            s0 = fmaf(qv.x, kv.x + rv.x, s0);
            s1 = fmaf(qv.y, kv.y + rv.y, s1);
            s2 = fmaf(qv.z, kv.z + rv.z, s2);
            s3 = fmaf(qv.w, kv.w + rv.w, s3);
        }
        float p = __expf((s0 + s1) + (s2 + s3) + drk[h * RLEN + jj]);
        p_s[t] = p;
        float ls = p;
#pragma unroll
        for (int off = 32; off > 0; off >>= 1)
            ls += __shfl_down(ls, off, 64);
        if ((t & 63) == 0) lred[t >> 6] = ls;
    }
    __syncthreads();
    {
        const int d = t & 63, g = t >> 6;
        float a0 = 0, a1 = 0;
        const float* vbase = qkv + (size_t)(b * NSEQ + c0 + g * 32) * HD3 + 1024 + h * 64 + d;
#pragma unroll
        for (int j2 = 0; j2 < 32; j2 += 2) {
            a0 = fmaf(p_s[g * 32 + j2],     vbase[(size_t)j2 * HD3],       a0);
            a1 = fmaf(p_s[g * 32 + j2 + 1], vbase[(size_t)(j2 + 1) * HD3], a1);
        }
        obuf[g][d] = a0 + a1;
    }
    __syncthreads();
    if (t < 64) {
        float o = (obuf[0][t] + obuf[1][t]) + (obuf[2][t] + obuf[3][t]);
        g_O[((size_t)chunk * 64 + bhi) * 64 + t] = o;
        if (t == 0) g_l[chunk * 64 + bhi] = lred[0] + lred[1];
    }
}

// ---------------------------------------------------------------------------
// Merge 3 ct-slices, normalize, emit ao as f16 (single-term out-proj).
// Rows i<4 (global rows) take their (O,l) from the 12 grows_part chunks.
// ---------------------------------------------------------------------------
__global__ __launch_bounds__(256) void norm_merge(
    const float* __restrict__ O_part, const float* __restrict__ l_part,
    const float* __restrict__ g_O, const float* __restrict__ g_l,
    _Float16* __restrict__ aoh)
{
    const int bh = blockIdx.y, b = bh >> 3, h = bh & 7;
    const int i = blockIdx.x * 16 + (threadIdx.x >> 4);
    const int d4 = threadIdx.x & 15;
    float ox = 0, oy = 0, oz = 0, ow = 0, l = 0;
    if (i < 4) {          // global row: sum the 12 column-chunk partials
        const int bhi = bh * 4 + i;
#pragma unroll
        for (int c = 0; c < 12; ++c) {
            const float* gp = g_O + ((size_t)c * 64 + bhi) * 64 + d4 * 4;
            ox += gp[0]; oy += gp[1]; oz += gp[2]; ow += gp[3];
            l += g_l[c * 64 + bhi];
        }
    } else {
#pragma unroll
        for (int s = 0; s < 3; ++s) {
            const float* Opp = O_part + (((size_t)s * 16 + bh) * NSEQ + i) * 64 + d4 * 4;
            float4 p = *(const float4*)Opp;
            ox += p.x; oy += p.y; oz += p.z; ow += p.w;
            l += l_part[((size_t)s * 16 + bh) * NSEQ + i];
        }
    }
    float inv = 1.f / l;
    union { _Float16 h[4]; ushort4 u; } cc;
    cc.h[0] = (_Float16)(ox * inv); cc.h[1] = (_Float16)(oy * inv);
    cc.h[2] = (_Float16)(oz * inv); cc.h[3] = (_Float16)(ow * inv);
    size_t o = ((size_t)(b * NSEQ + i)) * 512 + h * 64 + d4 * 4;
    *(ushort4*)(aoh + o) = cc.u;
}

// ---------------------------------------------------------------------------
extern "C" void kernel_launch(void* const* d_in, const int* in_sizes, int n_in,
                              void* d_out, int out_size, void* d_ws, size_t ws_size,
                              hipStream_t stream)
{
    const float* x    = (const float*)d_in[0];
    const float* Wq   = (const float*)d_in[1];
    const float* Wk   = (const float*)d_in[2];
    const float* Wv   = (const float*)d_in[3];
    const float* Wrel = (const float*)d_in[4];
    const float* cb   = (const float*)d_in[5];
    const float* rb   = (const float*)d_in[6];
    const float* Wo   = (const float*)d_in[7];
    const float* bo   = (const float*)d_in[8];
    const float* pe   = (const float*)d_in[9];
    float* out = (float*)d_out;

    float* ws = (float*)d_ws;
    float* qkv   = ws;                                   // [3072][1536] f32
    float* rkbuf = ws + 4718592;                         // [3071][512] f32
    float* drk   = ws + 6291456;                         // [8][3071] f32
    _Float16* aoh = (_Float16*)(ws + 6316032);           // [3072][512] f16
    _Float16* woh = (_Float16*)(ws + 7888896);           // WoT [1536][512] f16
    float* R = ws + 8675328;                             // aliased region
    _Float16* relbT = (_Float16*)R;                          // [16][12][512][128] f16
    _Float16* xh  = (_Float16*)R;                            // dead before relbT written
    _Float16* wqh = (_Float16*)(R + 4718592);                // WqkvT [1536][1536] f16
    float* g_O = R + 6291456;                            // [12][64][64] f32 (after relbT)
    float* g_l = R + 6340608;                            // [12][64] f32
    float* O_part = ws + 15753216;                       // [3][16][1536][64] f32
    float* l_part = ws + 20471808;                       // [3][16][1536] f32

    dim3 blk(256);
    splitf16<<<4608, blk, 0, stream>>>(x, xh, 1179648);
    wsplit_qkv16<<<dim3(8, 24, 3), blk, 0, stream>>>(Wq, Wk, Wv, wqh);
    wsplit_t16<<<dim3(24, 8), blk, 0, stream>>>(Wo, woh, 512, 1536, 0, 512, 1.f);
    gemm_f16k<<<dim3(24, 48), blk, 0, stream>>>(xh, wqh, nullptr, qkv,
                                                3072, 1536, 1536);
    gemm_f32<<<dim3(8, 48), blk, 0, stream>>>(pe, Wrel, nullptr, rkbuf, 3071, 512, 192, 1.f);
    drk_kernel<<<96, blk, 0, stream>>>(rkbuf, cb, rb, drk);
    relb_mfma<<<dim3(4, 12, 16), blk, 0, stream>>>(qkv, rkbuf, rb, relbT);
    attn_mfma<<<dim3(3, 12, 16), blk, 0, stream>>>(qkv, relbT, cb, O_part, l_part);
    attn_gcols<<<dim3(10, 16), dim3(128), 0, stream>>>(qkv, rkbuf, drk, cb, O_part, l_part);
    grows_part<<<dim3(12, 64), blk, 0, stream>>>(qkv, rkbuf, drk, cb, g_O, g_l);
    norm_merge<<<dim3(96, 16), blk, 0, stream>>>(O_part, l_part, g_O, g_l, aoh);
    gemm_f16k<<<dim3(24, 48), blk, 0, stream>>>(aoh, woh, bo, out,
                                                3072, 1536, 512);
}

// Round 5
// 242.812 us; speedup vs baseline: 1.2572x; 1.1046x over previous
//
#include <hip/hip_runtime.h>
#include <math.h>

#define NSEQ 1536
#define HD3  1536      // fused qkv row stride
#define RKLD 512       // rel_k row stride
#define RLEN 3071
#define NB   12

typedef __attribute__((ext_vector_type(8))) short bf16x8;
typedef __attribute__((ext_vector_type(4))) float f32x4;
typedef _Float16 f16x8 __attribute__((ext_vector_type(8)));
typedef _Float16 f16x4 __attribute__((ext_vector_type(4)));

__device__ __forceinline__ unsigned short f2bf(float f) {
    union { float f; unsigned u; } v; v.f = f;
    unsigned r = v.u + 0x7fffu + ((v.u >> 16) & 1u);
    return (unsigned short)(r >> 16);
}
__device__ __forceinline__ float bf2f(unsigned short s) {
    union { unsigned u; float f; } v; v.u = ((unsigned)s) << 16;
    return v.f;
}
__device__ __forceinline__ void cp16(const void* g, void* l) {
    __builtin_amdgcn_global_load_lds(
        (const __attribute__((address_space(1))) void*)g,
        (__attribute__((address_space(3))) void*)l, 16, 0, 0);
}

// LDS swizzles: keep 8-elem chunks contiguous; XOR chunk id with row bits to
// break power-of-2 stride bank conflicts.
#define KSWZ(row, d) ((row) * 64 + (((((d) >> 3) ^ ((row) & 7))) << 3) + ((d) & 7))
#define PSWZ(r, j)   ((r) * 128 + (((((j) >> 3) ^ ((r) & 15))) << 3) + ((j) & 7))
#define VSTR 136     // Vt row stride in elems (272B: 16B-aligned, non-pow2)

// ---------------------------------------------------------------------------
// fp32 -> f16 (single-term GEMM input)
// ---------------------------------------------------------------------------
__global__ __launch_bounds__(256) void splitf16(
    const float* __restrict__ X, _Float16* __restrict__ H, int n4)
{
    int i = blockIdx.x * 256 + threadIdx.x;
    if (i >= n4) return;
    float4 v = ((const float4*)X)[i];
    union { _Float16 h[4]; ushort4 u; } c;
    c.h[0] = (_Float16)v.x; c.h[1] = (_Float16)v.y;
    c.h[2] = (_Float16)v.z; c.h[3] = (_Float16)v.w;
    ((ushort4*)H)[i] = c.u;
}

// ---------------------------------------------------------------------------
// Weight transpose (generic): W[K][N] f32 -> T[n_off+N][ldt] f16
// ---------------------------------------------------------------------------
__device__ __forceinline__ void wsplit_body16(
    const float* __restrict__ W, _Float16* __restrict__ T,
    int K, int N, int n_off, int ldt, float scale, int bx, int by)
{
    __shared__ float tile[64][65];
    const int k0 = by * 64, n0 = bx * 64;
    const int t = threadIdx.x;
    const int rr = t >> 4, c4 = (t & 15) * 4;
#pragma unroll
    for (int p = 0; p < 4; ++p) {
        int r = p * 16 + rr;
        float4 v = *(const float4*)(W + (size_t)(k0 + r) * N + n0 + c4);
        tile[r][c4 + 0] = v.x; tile[r][c4 + 1] = v.y;
        tile[r][c4 + 2] = v.z; tile[r][c4 + 3] = v.w;
    }
    __syncthreads();
#pragma unroll
    for (int p = 0; p < 4; ++p) {
        int n = p * 16 + rr;
        union { _Float16 h[4]; ushort4 u; } cc;
        cc.h[0] = (_Float16)(tile[c4 + 0][n] * scale);
        cc.h[1] = (_Float16)(tile[c4 + 1][n] * scale);
        cc.h[2] = (_Float16)(tile[c4 + 2][n] * scale);
        cc.h[3] = (_Float16)(tile[c4 + 3][n] * scale);
        size_t o = (size_t)(n_off + n0 + n) * ldt + k0 + c4;
        *(ushort4*)(T + o) = cc.u;
    }
}

// One launch transposes all five weights: z=0..2 Wq/Wk/Wv, z=3 Wo, z=4 Wrel.
__global__ __launch_bounds__(256) void wsplit_all(
    const float* __restrict__ Wq, const float* __restrict__ Wk,
    const float* __restrict__ Wv, const float* __restrict__ Wo,
    const float* __restrict__ Wrel,
    _Float16* __restrict__ Tqkv, _Float16* __restrict__ To,
    _Float16* __restrict__ Trel)
{
    const int z = blockIdx.z;
    if (z < 3) {
        const float* W = (z == 0) ? Wq : (z == 1) ? Wk : Wv;
        wsplit_body16(W, Tqkv, 1536, 512, z * 512, 1536,
                      (z == 0) ? 0.125f : 1.f, blockIdx.x, blockIdx.y);
    } else if (z == 3) {
        // Wo: K=512, N=1536 -> bx in [0,24) = blockIdx.y, by in [0,8) = blockIdx.x
        wsplit_body16(Wo, To, 512, 1536, 0, 512, 1.f, blockIdx.y, blockIdx.x);
    } else {
        // Wrel: K=192, N=512 -> bx in [0,8), by in [0,3)
        if (blockIdx.y >= 3) return;   // uniform per block, before any barrier
        wsplit_body16(Wrel, Trel, 192, 512, 0, 192, 1.f, blockIdx.x, blockIdx.y);
    }
}

// ---------------------------------------------------------------------------
// Single-term f16 MFMA GEMM, 64x64 tile, BK=64: C = A·B^T (+bias).
// 2-buffer single-barrier; 32KB LDS; KSWZ; XCD swizzle. (R2-validated.)
// Also used for rel_k = pe @ Wrel with M padded 3071->3072 (pad row reads
// ws scratch; NaN output row 3071 is never consumed: all jj <= 3070).
// ---------------------------------------------------------------------------
__global__ __launch_bounds__(256) void gemm_f16k(
    const _Float16* __restrict__ A,   // [M][K] f16
    const _Float16* __restrict__ B,   // [N][K] f16 (pre-transposed weight)
    const float* __restrict__ bias, float* __restrict__ C,
    int M, int N, int K)
{
    __shared__ _Float16 sA[2][4096];    // [buf][64*64]
    __shared__ _Float16 sB[2][4096];
    const int t = threadIdx.x;
    const int wave = t >> 6, lane = t & 63;
    // XCD-aware bijective swizzle (nwg % 8 == 0 for all launches here)
    const int nwg = gridDim.x * gridDim.y;
    const int lin = blockIdx.y * gridDim.x + blockIdx.x;
    const int swz = (lin & 7) * (nwg >> 3) + (lin >> 3);
    const int bx = swz % gridDim.x, by = swz / gridDim.x;
    const int m0 = by * 64, n0 = bx * 64;
    const int wm = (wave >> 1) * 32, wn = (wave & 1) * 32;
    const int fr = lane & 15, quad = lane >> 4;

    f32x4 acc[2][2];
#pragma unroll
    for (int i = 0; i < 2; ++i)
#pragma unroll
        for (int j = 0; j < 2; ++j)
#pragma unroll
            for (int c = 0; c < 4; ++c) acc[i][j][c] = 0.f;

    const int nsteps = K >> 6;

// 2 cp16 per array per thread per stage; LDS dest linear (wave base + lane*16B),
// global source pre-swizzled so LDS slot (row, c) holds chunk c^(row&7) (KSWZ).
#define STAGE(k0, buf)                                                        \
    {                                                                         \
        _Pragma("unroll")                                                     \
        for (int it = 0; it < 2; ++it) {                                      \
            int cidx = it * 256 + t;                                          \
            int row = cidx >> 3, slot = cidx & 7;                             \
            int gch = slot ^ (row & 7);                                       \
            size_t goA = (size_t)(m0 + row) * K + (k0) + gch * 8;             \
            size_t goB = (size_t)(n0 + row) * K + (k0) + gch * 8;             \
            cp16(A + goA, &sA[buf][it * 2048 + wave * 512]);                  \
            cp16(B + goB, &sB[buf][it * 2048 + wave * 512]);                  \
        }                                                                     \
    }

    STAGE(0, 0);
    for (int s = 0; s < nsteps; ++s) {
        const int buf = s & 1;
        __syncthreads();
        if (s + 1 < nsteps) STAGE((s + 1) * 64, buf ^ 1);

        f16x8 fa[2][2], fb[2][2];
#pragma unroll
        for (int ti = 0; ti < 2; ++ti)
#pragma unroll
            for (int kc = 0; kc < 2; ++kc) {
                fa[ti][kc] = *(const f16x8*)&sA[buf][KSWZ(wm + ti * 16 + fr,
                                                          kc * 32 + quad * 8)];
                fb[ti][kc] = *(const f16x8*)&sB[buf][KSWZ(wn + ti * 16 + fr,
                                                          kc * 32 + quad * 8)];
            }
#pragma unroll
        for (int ti = 0; ti < 2; ++ti)
#pragma unroll
            for (int tj = 0; tj < 2; ++tj)
#pragma unroll
                for (int kc = 0; kc < 2; ++kc)
                    acc[ti][tj] = __builtin_amdgcn_mfma_f32_16x16x32_f16(
                        fa[ti][kc], fb[tj][kc], acc[ti][tj], 0, 0, 0);
    }
#undef STAGE

#pragma unroll
    for (int ti = 0; ti < 2; ++ti) {
        int rowb = m0 + wm + ti * 16 + quad * 4;
#pragma unroll
        for (int tj = 0; tj < 2; ++tj) {
            int col = n0 + wn + tj * 16 + fr;
            float bb = bias ? bias[col] : 0.f;
#pragma unroll
            for (int j2 = 0; j2 < 4; ++j2)
                C[(size_t)(rowb + j2) * N + col] = acc[ti][tj][j2] + bb;
        }
    }
}

// ---------------------------------------------------------------------------
// drk[h][jj] = sum_d (rpb[h,d]-rcb[h,d]) * rk[jj, h*64+d]
// ---------------------------------------------------------------------------
__global__ __launch_bounds__(256) void drk_kernel(
    const float* __restrict__ rkk, const float* __restrict__ cb,
    const float* __restrict__ rb, float* __restrict__ drk)
{
    int idx = blockIdx.x * 256 + threadIdx.x;
    if (idx >= 8 * RLEN) return;
    int jj = idx >> 3, h = idx & 7;
    const float* rrow = rkk + (size_t)jj * RKLD + h * 64;
    float s0 = 0, s1 = 0, s2 = 0, s3 = 0;
#pragma unroll
    for (int d4 = 0; d4 < 16; ++d4) {
        float4 rv = *(const float4*)(rrow + d4 * 4);
        float dx = rb[h * 64 + d4 * 4 + 0] - cb[h * 64 + d4 * 4 + 0];
        float dy = rb[h * 64 + d4 * 4 + 1] - cb[h * 64 + d4 * 4 + 1];
        float dz = rb[h * 64 + d4 * 4 + 2] - cb[h * 64 + d4 * 4 + 2];
        float dw = rb[h * 64 + d4 * 4 + 3] - cb[h * 64 + d4 * 4 + 3];
        s0 = fmaf(dx, rv.x, s0); s1 = fmaf(dy, rv.y, s1);
        s2 = fmaf(dz, rv.z, s2); s3 = fmaf(dw, rv.w, s3);
    }
    drk[h * RLEN + jj] = (s0 + s1) + (s2 + s3);
}

// ---------------------------------------------------------------------------
// Banded rel logits via f16 MFMA (single-term), stored SHIFTED+TRANSPOSED f16:
// relbT[bh][bi][jl][r], jl = ccg-127+r.
// ---------------------------------------------------------------------------
__global__ __launch_bounds__(256) void relb_mfma(
    const float* __restrict__ qkv, const float* __restrict__ rkk,
    const float* __restrict__ rb, _Float16* __restrict__ relbT)
{
    __shared__ _Float16 sR[8192];   // 128 band rows x 64 d
    const int ct = blockIdx.x, bi = blockIdx.y, bh = blockIdx.z;
    const int b = bh >> 3, h = bh & 7;
    const int i0 = bi * 128;
    const int c0 = (bi == 0) ? 0 : (bi - 1) * 128;
    const int jjbase = c0 - i0 - 127 + (NSEQ - 1) + ct * 128;  // in [1280,1920)
    const int t = threadIdx.x;
    const int wave = t >> 6, lane = t & 63;
    const int fr = lane & 15, quad = lane >> 4;

    // ---- stage rk band (f16, swizzled [cc][64]) ----
#pragma unroll
    for (int it = 0; it < 8; ++it) {
        int lin = it * 256 + t;            // 0..2047
        int row = lin >> 4, d4 = (lin & 15) * 4;
        const float* rp = rkk + (size_t)(jjbase + row) * RKLD + h * 64 + d4;
        float4 v = *(const float4*)rp;
        union { _Float16 h[4]; ushort4 u; } cc;
        cc.h[0] = (_Float16)v.x; cc.h[1] = (_Float16)v.y;
        cc.h[2] = (_Float16)v.z; cc.h[3] = (_Float16)v.w;
        *(ushort4*)&sR[KSWZ(row, d4)] = cc.u;
    }
    // ---- Q + rel-pos-bias fragments (f16) ----
    f16x8 qf[2][2];
    {
        const float* Qg = qkv + ((size_t)(b * NSEQ + i0)) * HD3 + h * 64;
#pragma unroll
        for (int ti = 0; ti < 2; ++ti)
#pragma unroll
            for (int kc = 0; kc < 2; ++kc) {
                int m = wave * 32 + ti * 16 + fr;
                int k8 = kc * 32 + quad * 8;
                const float* qp = Qg + (size_t)m * HD3 + k8;
                const float* cp = rb + h * 64 + k8;
                float4 qa = *(const float4*)qp,  qb = *(const float4*)(qp + 4);
                float4 ca = *(const float4*)cp,  c2 = *(const float4*)(cp + 4);
                _Float16 hx[8] = {
                    (_Float16)(qa.x + ca.x), (_Float16)(qa.y + ca.y),
                    (_Float16)(qa.z + ca.z), (_Float16)(qa.w + ca.w),
                    (_Float16)(qb.x + c2.x), (_Float16)(qb.y + c2.y),
                    (_Float16)(qb.z + c2.z), (_Float16)(qb.w + c2.w)};
                qf[ti][kc] = *(f16x8*)hx;
            }
    }
    __syncthreads();

    // ---- S = (Q+rpb) · rk^T ----
    f32x4 sacc[2][8];
#pragma unroll
    for (int i = 0; i < 2; ++i)
#pragma unroll
        for (int j = 0; j < 8; ++j)
#pragma unroll
            for (int c = 0; c < 4; ++c) sacc[i][j][c] = 0.f;

#pragma unroll
    for (int kc = 0; kc < 2; ++kc) {
        f16x8 bv[8];
#pragma unroll
        for (int tj = 0; tj < 8; ++tj)
            bv[tj] = *(const f16x8*)&sR[KSWZ(tj * 16 + fr, kc * 32 + quad * 8)];
#pragma unroll
        for (int ti = 0; ti < 2; ++ti)
#pragma unroll
            for (int tj = 0; tj < 8; ++tj)
                sacc[ti][tj] = __builtin_amdgcn_mfma_f32_16x16x32_f16(
                    qf[ti][kc], bv[tj], sacc[ti][tj], 0, 0, 0);
    }

    // ---- shifted scatter-store to relbT ----
    size_t bb_ = ((size_t)bh * NB + bi) * 512;
#pragma unroll
    for (int ti = 0; ti < 2; ++ti) {
        int mr = wave * 32 + ti * 16 + quad * 4;
#pragma unroll
        for (int tj = 0; tj < 8; ++tj) {
            int ccg = ct * 128 + tj * 16 + fr;
#pragma unroll
            for (int reg = 0; reg < 4; ++reg) {
                int r = mr + reg;
                int jl = ccg - 127 + r;            // < 512 always
                if (jl >= 0)
                    relbT[(bb_ + jl) * 128 + r] = (_Float16)sacc[ti][tj][reg];
            }
        }
    }
}

// ---------------------------------------------------------------------------
// MFMA flash attention (local window) + FUSED global-column contribution.
// QK^T f16 (f32 accum). P bf16 (unnormalized softmax: p reaches ~1e13, f16
// overflows — R3). V bf16-hi; PV bf16 MFMA.
// ct==0 & bi>=2 blocks also fold in the 4 global columns (was attn_gcols):
// p_g/vg/lg computed pre-barrier into 3.5KB LDS, added at the O/l store.
// ---------------------------------------------------------------------------
__global__ __launch_bounds__(256) void attn_mfma(
    const float* __restrict__ qkv, const _Float16* __restrict__ relbT,
    const float* __restrict__ rkbuf, const float* __restrict__ drk,
    const float* __restrict__ cb, float* __restrict__ O_part,
    float* __restrict__ l_part)
{
    __shared__ unsigned short sKP[16384];   // K f16 [0:8192] -> P bf16 (PSWZ, full)
    __shared__ unsigned short sVt[64 * VSTR];  // V^T bf16-hi [d][VSTR]
    __shared__ float p_g[128 * 4];          // fused-gcols p per (row, j)
    __shared__ __align__(16) float vg[4 * 64];  // global V rows 0..3
    __shared__ float lg[128];               // fused-gcols l per row
    const int ct = blockIdx.x, bi = blockIdx.y, bh = blockIdx.z;
    const int b = bh >> 3, h = bh & 7;
    const int i0 = bi * 128;
    const int c0 = (bi == 0) ? 0 : (bi - 1) * 128;
    const int c1 = (bi == NB - 1) ? NSEQ : (bi + 2) * 128;
    const int ctile = c0 + ct * 128;
    const int t = threadIdx.x;
    const int wave = t >> 6, lane = t & 63;
    const int fr = lane & 15, quad = lane >> 4;

    float* Op = O_part + (((size_t)ct * 16 + bh) * NSEQ + i0) * 64;
    float* lp = l_part + ((size_t)ct * 16 + bh) * NSEQ + i0;

    if (ctile >= c1) {      // inactive edge tile: zero slice
        for (int k2 = t; k2 < 8192; k2 += 256) Op[k2] = 0.f;
        if (t < 128) lp[t] = 0.f;
        return;
    }

    const bool do_g = (ct == 0 && bi >= 2);

    // ---- stage K (f16 bits, swizzled [j][64]) ----
    {
        const float* Kg = qkv + ((size_t)(b * NSEQ + ctile)) * HD3 + 512 + h * 64;
#pragma unroll
        for (int it = 0; it < 8; ++it) {
            int lin = it * 256 + t;            // 0..2047
            int row = lin >> 4, d4 = (lin & 15) * 4;
            float4 v = *(const float4*)(Kg + (size_t)row * HD3 + d4);
            union { _Float16 h[4]; ushort4 u; } cc;
            cc.h[0] = (_Float16)v.x; cc.h[1] = (_Float16)v.y;
            cc.h[2] = (_Float16)v.z; cc.h[3] = (_Float16)v.w;
            *(ushort4*)&sKP[KSWZ(row, d4)] = cc.u;
        }
    }
    // ---- stage V transposed (bf16-hi, [d][VSTR]) ----
    {
        const float* Vg = qkv + ((size_t)(b * NSEQ + ctile)) * HD3 + 1024 + h * 64;
#pragma unroll
        for (int it = 0; it < 2; ++it) {
            int lin = it * 256 + t;            // 0..511
            int r4 = (lin >> 4) * 4, d4 = (lin & 15) * 4;
            float4 v0 = *(const float4*)(Vg + (size_t)(r4 + 0) * HD3 + d4);
            float4 v1 = *(const float4*)(Vg + (size_t)(r4 + 1) * HD3 + d4);
            float4 v2 = *(const float4*)(Vg + (size_t)(r4 + 2) * HD3 + d4);
            float4 v3 = *(const float4*)(Vg + (size_t)(r4 + 3) * HD3 + d4);
            const float* p0 = (const float*)&v0;
            const float* p1 = (const float*)&v1;
            const float* p2 = (const float*)&v2;
            const float* p3 = (const float*)&v3;
#pragma unroll
            for (int dd = 0; dd < 4; ++dd) {
                ushort4 hh;
                hh.x = f2bf(p0[dd]); hh.y = f2bf(p1[dd]);
                hh.z = f2bf(p2[dd]); hh.w = f2bf(p3[dd]);
                *(ushort4*)&sVt[(d4 + dd) * VSTR + r4] = hh;
            }
        }
    }
    // ---- fused global-column (cols 0..3) contribution ----
    if (do_g) {
        if (t < 128) {
            const int r = t;
            const int i = i0 + r;
            const int jjb = NSEQ - 1 - i;       // jj for j=0; j adds +j
            const float* qrow = qkv + (size_t)(b * NSEQ + i) * HD3 + h * 64;
            const float* krow = qkv + (size_t)(b * NSEQ) * HD3 + 512 + h * 64;
            const float* rrow = rkbuf + (size_t)jjb * RKLD + h * 64;
            float s[4] = {0.f, 0.f, 0.f, 0.f};
#pragma unroll
            for (int d4 = 0; d4 < 16; ++d4) {
                float4 qv = *(const float4*)(qrow + d4 * 4);
                float4 cv = *(const float4*)(cb + h * 64 + d4 * 4);
                float q0 = qv.x + cv.x, q1 = qv.y + cv.y;
                float q2 = qv.z + cv.z, q3 = qv.w + cv.w;
#pragma unroll
                for (int j = 0; j < 4; ++j) {
                    float4 kv = *(const float4*)(krow + (size_t)j * HD3 + d4 * 4);
                    float4 rv = *(const float4*)(rrow + (size_t)j * RKLD + d4 * 4);
                    s[j] = fmaf(q0, kv.x + rv.x, s[j]);
                    s[j] = fmaf(q1, kv.y + rv.y, s[j]);
                    s[j] = fmaf(q2, kv.z + rv.z, s[j]);
                    s[j] = fmaf(q3, kv.w + rv.w, s[j]);
                }
            }
            float l = 0.f;
#pragma unroll
            for (int j = 0; j < 4; ++j) {
                float p = __expf(s[j] + drk[h * RLEN + jjb + j]);
                p_g[r * 4 + j] = p;
                l += p;
            }
            lg[r] = l;
        } else {
            int u = (t - 128) * 2;
#pragma unroll
            for (int w = 0; w < 2; ++w) {
                int idx = u + w;               // j*64 + d
                vg[idx] = qkv[(size_t)(b * NSEQ + (idx >> 6)) * HD3 + 1024
                              + h * 64 + (idx & 63)];
            }
        }
    }
    // ---- Q fragments in registers (q + content bias, f16) ----
    f16x8 qf[2][2];
    {
        const float* Qg = qkv + ((size_t)(b * NSEQ + i0)) * HD3 + h * 64;
#pragma unroll
        for (int ti = 0; ti < 2; ++ti)
#pragma unroll
            for (int kc = 0; kc < 2; ++kc) {
                int m = wave * 32 + ti * 16 + fr;
                int k8 = kc * 32 + quad * 8;
                const float* qp = Qg + (size_t)m * HD3 + k8;
                const float* cp = cb + h * 64 + k8;
                float4 qa = *(const float4*)qp,  qb = *(const float4*)(qp + 4);
                float4 ca = *(const float4*)cp,  c2 = *(const float4*)(cp + 4);
                _Float16 hx[8] = {
                    (_Float16)(qa.x + ca.x), (_Float16)(qa.y + ca.y),
                    (_Float16)(qa.z + ca.z), (_Float16)(qa.w + ca.w),
                    (_Float16)(qb.x + c2.x), (_Float16)(qb.y + c2.y),
                    (_Float16)(qb.z + c2.z), (_Float16)(qb.w + c2.w)};
                qf[ti][kc] = *(f16x8*)hx;
            }
    }
    __syncthreads();

    // ---- S = Q K^T (f16 MFMA, f32 accum) ----
    f32x4 sacc[2][8];
#pragma unroll
    for (int i = 0; i < 2; ++i)
#pragma unroll
        for (int j = 0; j < 8; ++j)
#pragma unroll
            for (int c = 0; c < 4; ++c) sacc[i][j][c] = 0.f;

#pragma unroll
    for (int kc = 0; kc < 2; ++kc) {
        f16x8 bv[8];
#pragma unroll
        for (int tj = 0; tj < 8; ++tj)
            bv[tj] = *(const f16x8*)&sKP[KSWZ(tj * 16 + fr, kc * 32 + quad * 8)];
#pragma unroll
        for (int ti = 0; ti < 2; ++ti)
#pragma unroll
            for (int tj = 0; tj < 8; ++tj)
                sacc[ti][tj] = __builtin_amdgcn_mfma_f32_16x16x32_f16(
                    qf[ti][kc], bv[tj], sacc[ti][tj], 0, 0, 0);
    }
    __syncthreads();   // all waves done reading K before P overwrites it

    // ---- rel + exp -> P (bf16, swizzled [r][j]); row-sums ----
    const _Float16* relbase = relbT + (((size_t)bh * NB + bi) * 512 + ct * 128) * 128;
    float lsum[2][4] = {{0.f, 0.f, 0.f, 0.f}, {0.f, 0.f, 0.f, 0.f}};
#pragma unroll
    for (int ti = 0; ti < 2; ++ti) {
        int mr = wave * 32 + ti * 16 + quad * 4;
#pragma unroll
        for (int tj = 0; tj < 8; ++tj) {
            int j = tj * 16 + fr;
            f16x4 rl = *(const f16x4*)&relbase[(size_t)j * 128 + mr];
#pragma unroll
            for (int reg = 0; reg < 4; ++reg) {
                int r = mr + reg;
                float p = __expf(sacc[ti][tj][reg] + (float)rl[reg]);
                unsigned short pb = f2bf(p);
                lsum[ti][reg] += bf2f(pb);     // l consistent with bf16 P
                sKP[PSWZ(r, j)] = pb;
            }
        }
    }
#pragma unroll
    for (int m2 = 1; m2 < 16; m2 <<= 1)
#pragma unroll
        for (int ti = 0; ti < 2; ++ti)
#pragma unroll
            for (int reg = 0; reg < 4; ++reg)
                lsum[ti][reg] += __shfl_xor(lsum[ti][reg], m2, 64);
    if (fr == 0) {
#pragma unroll
        for (int ti = 0; ti < 2; ++ti) {
            int mr = wave * 32 + ti * 16 + quad * 4;
#pragma unroll
            for (int reg = 0; reg < 4; ++reg)
                lp[mr + reg] = lsum[ti][reg] + (do_g ? lg[mr + reg] : 0.f);
        }
    }

    // ---- O^T = Vt x P^T (bf16 MFMA; each wave consumes only its own P rows) ----
    f32x4 oacc[4][2];
#pragma unroll
    for (int i = 0; i < 4; ++i)
#pragma unroll
        for (int j = 0; j < 2; ++j)
#pragma unroll
            for (int c = 0; c < 4; ++c) oacc[i][j][c] = 0.f;

#pragma unroll
    for (int kc = 0; kc < 4; ++kc) {
        bf16x8 pbv[2];
#pragma unroll
        for (int rt2 = 0; rt2 < 2; ++rt2) {
            int r = (wave * 2 + rt2) * 16 + fr;
            pbv[rt2] = *(const bf16x8*)&sKP[PSWZ(r, kc * 32 + quad * 8)];
        }
#pragma unroll
        for (int dt = 0; dt < 4; ++dt) {
            bf16x8 av = *(const bf16x8*)&sVt[(dt * 16 + fr) * VSTR + kc * 32 + quad * 8];
#pragma unroll
            for (int rt2 = 0; rt2 < 2; ++rt2)
                oacc[dt][rt2] = __builtin_amdgcn_mfma_f32_16x16x32_bf16(
                    av, pbv[rt2], oacc[dt][rt2], 0, 0, 0);
        }
    }
#pragma unroll
    for (int rt2 = 0; rt2 < 2; ++rt2) {
        int r = (wave * 2 + rt2) * 16 + fr;
        float pg0 = 0.f, pg1 = 0.f, pg2 = 0.f, pg3 = 0.f;
        if (do_g) {
            pg0 = p_g[r * 4 + 0]; pg1 = p_g[r * 4 + 1];
            pg2 = p_g[r * 4 + 2]; pg3 = p_g[r * 4 + 3];
        }
#pragma unroll
        for (int dt = 0; dt < 4; ++dt) {
            int d = dt * 16 + quad * 4;
            float4 ov = make_float4(oacc[dt][rt2][0], oacc[dt][rt2][1],
                                    oacc[dt][rt2][2], oacc[dt][rt2][3]);
            if (do_g) {
                float4 v0 = *(const float4*)&vg[0 * 64 + d];
                float4 v1 = *(const float4*)&vg[1 * 64 + d];
                float4 v2 = *(const float4*)&vg[2 * 64 + d];
                float4 v3 = *(const float4*)&vg[3 * 64 + d];
                ov.x += pg0 * v0.x + pg1 * v1.x + pg2 * v2.x + pg3 * v3.x;
                ov.y += pg0 * v0.y + pg1 * v1.y + pg2 * v2.y + pg3 * v3.y;
                ov.z += pg0 * v0.z + pg1 * v1.z + pg2 * v2.z + pg3 * v3.z;
                ov.w += pg0 * v0.w + pg1 * v1.w + pg2 * v2.w + pg3 * v3.w;
            }
            *(float4*)(Op + (size_t)r * 64 + d) = ov;
        }
    }
}

// ---------------------------------------------------------------------------
// Global-ROW attention partials: grid (12 col-chunks, 64 bhi), 256 thr.
// ---------------------------------------------------------------------------
__global__ __launch_bounds__(256) void grows_part(
    const float* __restrict__ qkv, const float* __restrict__ rkk,
    const float* __restrict__ drk, const float* __restrict__ cb,
    float* __restrict__ g_O, float* __restrict__ g_l)
{
    __shared__ float qc_s[64];
    __shared__ float p_s[128];
    __shared__ float obuf[4][64];
    __shared__ float lred[2];
    const int chunk = blockIdx.x;        // 0..11
    const int bhi = blockIdx.y;          // 0..63
    const int i = bhi & 3, h = (bhi >> 2) & 7, b = bhi >> 5;
    const int t = threadIdx.x;
    const int c0 = chunk * 128;
    if (t < 64)
        qc_s[t] = qkv[(size_t)(b * NSEQ + i) * HD3 + h * 64 + t] + cb[h * 64 + t];
    __syncthreads();
    if (t < 128) {
        int j = c0 + t;
        const float* krow = qkv + (size_t)(b * NSEQ + j) * HD3 + 512 + h * 64;
        int jj = j - i + (NSEQ - 1);
        const float* rrow = rkk + (size_t)jj * RKLD + h * 64;
        float s0 = 0, s1 = 0, s2 = 0, s3 = 0;
#pragma unroll
        for (int d4 = 0; d4 < 16; ++d4) {
            float4 kv = *(const float4*)(krow + d4 * 4);
            float4 rv = *(const float4*)(rrow + d4 * 4);
            float4 qv = *(const float4*)(&qc_s[d4 * 4]);
            s0 = fmaf(qv.x, kv.x + rv.x, s0);
            s1 = fmaf(qv.y, kv.y + rv.y, s1);
            s2 = fmaf(qv.z, kv.z + rv.z, s2);
            s3 = fmaf(qv.w, kv.w + rv.w, s3);
        }
        float p = __expf((s0 + s1) + (s2 + s3) + drk[h * RLEN + jj]);
        p_s[t] = p;
        float ls = p;
#pragma unroll
        for (int off = 32; off > 0; off >>= 1)
            ls += __shfl_down(ls, off, 64);
        if ((t & 63) == 0) lred[t >> 6] = ls;
    }
    __syncthreads();
    {
        const int d = t & 63, g = t >> 6;
        float a0 = 0, a1 = 0;
        const float* vbase = qkv + (size_t)(b * NSEQ + c0 + g * 32) * HD3 + 1024 + h * 64 + d;
#pragma unroll
        for (int j2 = 0; j2 < 32; j2 += 2) {
            a0 = fmaf(p_s[g * 32 + j2],     vbase[(size_t)j2 * HD3],       a0);
            a1 = fmaf(p_s[g * 32 + j2 + 1], vbase[(size_t)(j2 + 1) * HD3], a1);
        }
        obuf[g][d] = a0 + a1;
    }
    __syncthreads();
    if (t < 64) {
        float o = (obuf[0][t] + obuf[1][t]) + (obuf[2][t] + obuf[3][t]);
        g_O[((size_t)chunk * 64 + bhi) * 64 + t] = o;
        if (t == 0) g_l[chunk * 64 + bhi] = lred[0] + lred[1];
    }
}

// ---------------------------------------------------------------------------
// Merge 3 ct-slices, normalize, emit ao as f16 (single-term out-proj).
// Rows i<4 (global rows) take their (O,l) from the 12 grows_part chunks.
// ---------------------------------------------------------------------------
__global__ __launch_bounds__(256) void norm_merge(
    const float* __restrict__ O_part, const float* __restrict__ l_part,
    const float* __restrict__ g_O, const float* __restrict__ g_l,
    _Float16* __restrict__ aoh)
{
    const int bh = blockIdx.y, b = bh >> 3, h = bh & 7;
    const int i = blockIdx.x * 16 + (threadIdx.x >> 4);
    const int d4 = threadIdx.x & 15;
    float ox = 0, oy = 0, oz = 0, ow = 0, l = 0;
    if (i < 4) {          // global row: sum the 12 column-chunk partials
        const int bhi = bh * 4 + i;
#pragma unroll
        for (int c = 0; c < 12; ++c) {
            const float* gp = g_O + ((size_t)c * 64 + bhi) * 64 + d4 * 4;
            ox += gp[0]; oy += gp[1]; oz += gp[2]; ow += gp[3];
            l += g_l[c * 64 + bhi];
        }
    } else {
#pragma unroll
        for (int s = 0; s < 3; ++s) {
            const float* Opp = O_part + (((size_t)s * 16 + bh) * NSEQ + i) * 64 + d4 * 4;
            float4 p = *(const float4*)Opp;
            ox += p.x; oy += p.y; oz += p.z; ow += p.w;
            l += l_part[((size_t)s * 16 + bh) * NSEQ + i];
        }
    }
    float inv = 1.f / l;
    union { _Float16 h[4]; ushort4 u; } cc;
    cc.h[0] = (_Float16)(ox * inv); cc.h[1] = (_Float16)(oy * inv);
    cc.h[2] = (_Float16)(oz * inv); cc.h[3] = (_Float16)(ow * inv);
    size_t o = ((size_t)(b * NSEQ + i)) * 512 + h * 64 + d4 * 4;
    *(ushort4*)(aoh + o) = cc.u;
}

// ---------------------------------------------------------------------------
extern "C" void kernel_launch(void* const* d_in, const int* in_sizes, int n_in,
                              void* d_out, int out_size, void* d_ws, size_t ws_size,
                              hipStream_t stream)
{
    const float* x    = (const float*)d_in[0];
    const float* Wq   = (const float*)d_in[1];
    const float* Wk   = (const float*)d_in[2];
    const float* Wv   = (const float*)d_in[3];
    const float* Wrel = (const float*)d_in[4];
    const float* cb   = (const float*)d_in[5];
    const float* rb   = (const float*)d_in[6];
    const float* Wo   = (const float*)d_in[7];
    const float* bo   = (const float*)d_in[8];
    const float* pe   = (const float*)d_in[9];
    float* out = (float*)d_out;

    float* ws = (float*)d_ws;
    float* qkv   = ws;                                   // [3072][1536] f32
    float* rkbuf = ws + 4718592;                         // [3072][512] f32 (row 3071 scratch)
    float* drk   = ws + 6291456;                         // [8][3071] f32
    _Float16* aoh = (_Float16*)(ws + 6316032);           // [3072][512] f16
    _Float16* woh = (_Float16*)(ws + 7888896);           // WoT [1536][512] f16
    float* R = ws + 8675328;                             // aliased region
    _Float16* relbT = (_Float16*)R;                          // [16][12][512][128] f16
    _Float16* xh  = (_Float16*)R;                            // dead before relbT written
    _Float16* wqh = (_Float16*)(R + 4718592);                // WqkvT [1536][1536] f16
    float* g_O = R + 6291456;                            // [12][64][64] f32 (after relbT)
    float* g_l = R + 6340608;                            // [12][64] f32
    float* O_part = ws + 15753216;                       // [3][16][1536][64] f32
    float* l_part = ws + 20471808;                       // [3][16][1536] f32
    _Float16* peh   = (_Float16*)(ws + 20545536);        // [3072][192] f16 (row 3071 scratch)
    _Float16* wrelT = (_Float16*)(ws + 20840448);        // WrelT [512][192] f16

    dim3 blk(256);
    splitf16<<<4608, blk, 0, stream>>>(x, xh, 1179648);
    splitf16<<<576, blk, 0, stream>>>(pe, peh, 147408);        // 3071*192/4
    wsplit_all<<<dim3(8, 24, 5), blk, 0, stream>>>(Wq, Wk, Wv, Wo, Wrel,
                                                   wqh, woh, wrelT);
    gemm_f16k<<<dim3(24, 48), blk, 0, stream>>>(xh, wqh, nullptr, qkv,
                                                3072, 1536, 1536);
    gemm_f16k<<<dim3(8, 48), blk, 0, stream>>>(peh, wrelT, nullptr, rkbuf,
                                               3072, 512, 192);
    drk_kernel<<<96, blk, 0, stream>>>(rkbuf, cb, rb, drk);
    relb_mfma<<<dim3(4, 12, 16), blk, 0, stream>>>(qkv, rkbuf, rb, relbT);
    attn_mfma<<<dim3(3, 12, 16), blk, 0, stream>>>(qkv, relbT, rkbuf, drk, cb,
                                                   O_part, l_part);
    grows_part<<<dim3(12, 64), blk, 0, stream>>>(qkv, rkbuf, drk, cb, g_O, g_l);
    norm_merge<<<dim3(96, 16), blk, 0, stream>>>(O_part, l_part, g_O, g_l, aoh);
    gemm_f16k<<<dim3(24, 48), blk, 0, stream>>>(aoh, woh, bo, out,
                                                3072, 1536, 512);
}

// Round 6
// 227.310 us; speedup vs baseline: 1.3429x; 1.0682x over previous
//
#include <hip/hip_runtime.h>
#include <math.h>

#define NSEQ 1536
#define HD3  1536      // fused qkv row stride
#define RKLD 512       // rel_k row stride
#define RLEN 3071
#define NB   12

typedef __attribute__((ext_vector_type(8))) short bf16x8;
typedef __attribute__((ext_vector_type(4))) float f32x4;
typedef _Float16 f16x8 __attribute__((ext_vector_type(8)));
typedef _Float16 f16x4 __attribute__((ext_vector_type(4)));

__device__ __forceinline__ unsigned short f2bf(float f) {
    union { float f; unsigned u; } v; v.f = f;
    unsigned r = v.u + 0x7fffu + ((v.u >> 16) & 1u);
    return (unsigned short)(r >> 16);
}
__device__ __forceinline__ float bf2f(unsigned short s) {
    union { unsigned u; float f; } v; v.u = ((unsigned)s) << 16;
    return v.f;
}
__device__ __forceinline__ unsigned short f2h(float f) {
    union { _Float16 h; unsigned short u; } c; c.h = (_Float16)f; return c.u;
}
__device__ __forceinline__ void cp16(const void* g, void* l) {
    __builtin_amdgcn_global_load_lds(
        (const __attribute__((address_space(1))) void*)g,
        (__attribute__((address_space(3))) void*)l, 16, 0, 0);
}

// LDS swizzles: keep 8-elem chunks contiguous; XOR chunk id with row bits to
// break power-of-2 stride bank conflicts.
#define KSWZ(row, d) ((row) * 64 + (((((d) >> 3) ^ ((row) & 7))) << 3) + ((d) & 7))
#define PSWZ(r, j)   ((r) * 128 + (((((j) >> 3) ^ ((r) & 15))) << 3) + ((j) & 7))
#define VSTR 136     // Vt row stride in elems (272B: 16B-aligned, non-pow2)

// ---------------------------------------------------------------------------
// fp32 -> f16: x (4608 blocks) and pos_embed (576 blocks) in one launch.
// ---------------------------------------------------------------------------
__global__ __launch_bounds__(256) void split2_f16(
    const float* __restrict__ X, _Float16* __restrict__ HX,
    const float* __restrict__ P, _Float16* __restrict__ HP)
{
    const int bid = blockIdx.x;
    const float* src; _Float16* dst; int i;
    if (bid < 4608) {                    // 4608*256 == 1179648 exactly
        i = bid * 256 + threadIdx.x;
        src = X; dst = HX;
    } else {
        i = (bid - 4608) * 256 + threadIdx.x;
        if (i >= 147408) return;         // 3071*192/4
        src = P; dst = HP;
    }
    float4 v = ((const float4*)src)[i];
    union { _Float16 h[4]; ushort4 u; } c;
    c.h[0] = (_Float16)v.x; c.h[1] = (_Float16)v.y;
    c.h[2] = (_Float16)v.z; c.h[3] = (_Float16)v.w;
    ((ushort4*)dst)[i] = c.u;
}

// ---------------------------------------------------------------------------
// Weight transpose (generic): W[K][N] f32 -> T[n_off+N][ldt] f16
// ---------------------------------------------------------------------------
__device__ __forceinline__ void wsplit_body16(
    const float* __restrict__ W, _Float16* __restrict__ T,
    int K, int N, int n_off, int ldt, float scale, int bx, int by)
{
    __shared__ float tile[64][65];
    const int k0 = by * 64, n0 = bx * 64;
    const int t = threadIdx.x;
    const int rr = t >> 4, c4 = (t & 15) * 4;
#pragma unroll
    for (int p = 0; p < 4; ++p) {
        int r = p * 16 + rr;
        float4 v = *(const float4*)(W + (size_t)(k0 + r) * N + n0 + c4);
        tile[r][c4 + 0] = v.x; tile[r][c4 + 1] = v.y;
        tile[r][c4 + 2] = v.z; tile[r][c4 + 3] = v.w;
    }
    __syncthreads();
#pragma unroll
    for (int p = 0; p < 4; ++p) {
        int n = p * 16 + rr;
        union { _Float16 h[4]; ushort4 u; } cc;
        cc.h[0] = (_Float16)(tile[c4 + 0][n] * scale);
        cc.h[1] = (_Float16)(tile[c4 + 1][n] * scale);
        cc.h[2] = (_Float16)(tile[c4 + 2][n] * scale);
        cc.h[3] = (_Float16)(tile[c4 + 3][n] * scale);
        size_t o = (size_t)(n_off + n0 + n) * ldt + k0 + c4;
        *(ushort4*)(T + o) = cc.u;
    }
}

// One launch transposes all five weights: z=0..2 Wq/Wk/Wv, z=3 Wo, z=4 Wrel.
__global__ __launch_bounds__(256) void wsplit_all(
    const float* __restrict__ Wq, const float* __restrict__ Wk,
    const float* __restrict__ Wv, const float* __restrict__ Wo,
    const float* __restrict__ Wrel,
    _Float16* __restrict__ Tqkv, _Float16* __restrict__ To,
    _Float16* __restrict__ Trel)
{
    const int z = blockIdx.z;
    if (z < 3) {
        const float* W = (z == 0) ? Wq : (z == 1) ? Wk : Wv;
        wsplit_body16(W, Tqkv, 1536, 512, z * 512, 1536,
                      (z == 0) ? 0.125f : 1.f, blockIdx.x, blockIdx.y);
    } else if (z == 3) {
        wsplit_body16(Wo, To, 512, 1536, 0, 512, 1.f, blockIdx.y, blockIdx.x);
    } else {
        if (blockIdx.y >= 3) return;   // uniform per block, before any barrier
        wsplit_body16(Wrel, Trel, 192, 512, 0, 192, 1.f, blockIdx.x, blockIdx.y);
    }
}

// ---------------------------------------------------------------------------
// Single-term f16 MFMA GEMM, 64x64 tile, BK=64: C = A·B^T (+bias).
// 2-buffer single-barrier; 32KB LDS; KSWZ; XCD swizzle.
// omode 0: C f32 + bias. omode 1: QKV split store — cols<1024 f16 (Q,K),
// cols>=1024 bf16 (V: must pair with bf16 P in the PV MFMA). omode 2: f16.
// Rounding moved from consumers to this epilogue — same error, half traffic.
// ---------------------------------------------------------------------------
__global__ __launch_bounds__(256) void gemm_f16k(
    const _Float16* __restrict__ A,   // [M][K] f16
    const _Float16* __restrict__ B,   // [N][K] f16 (pre-transposed weight)
    const float* __restrict__ bias, void* __restrict__ C,
    int M, int N, int K, int omode)
{
    __shared__ _Float16 sA[2][4096];    // [buf][64*64]
    __shared__ _Float16 sB[2][4096];
    const int t = threadIdx.x;
    const int wave = t >> 6, lane = t & 63;
    // XCD-aware bijective swizzle (nwg % 8 == 0 for all launches here)
    const int nwg = gridDim.x * gridDim.y;
    const int lin = blockIdx.y * gridDim.x + blockIdx.x;
    const int swz = (lin & 7) * (nwg >> 3) + (lin >> 3);
    const int bx = swz % gridDim.x, by = swz / gridDim.x;
    const int m0 = by * 64, n0 = bx * 64;
    const int wm = (wave >> 1) * 32, wn = (wave & 1) * 32;
    const int fr = lane & 15, quad = lane >> 4;

    f32x4 acc[2][2];
#pragma unroll
    for (int i = 0; i < 2; ++i)
#pragma unroll
        for (int j = 0; j < 2; ++j)
#pragma unroll
            for (int c = 0; c < 4; ++c) acc[i][j][c] = 0.f;

    const int nsteps = K >> 6;

#define STAGE(k0, buf)                                                        \
    {                                                                         \
        _Pragma("unroll")                                                     \
        for (int it = 0; it < 2; ++it) {                                      \
            int cidx = it * 256 + t;                                          \
            int row = cidx >> 3, slot = cidx & 7;                             \
            int gch = slot ^ (row & 7);                                       \
            size_t goA = (size_t)(m0 + row) * K + (k0) + gch * 8;             \
            size_t goB = (size_t)(n0 + row) * K + (k0) + gch * 8;             \
            cp16(A + goA, &sA[buf][it * 2048 + wave * 512]);                  \
            cp16(B + goB, &sB[buf][it * 2048 + wave * 512]);                  \
        }                                                                     \
    }

    STAGE(0, 0);
    for (int s = 0; s < nsteps; ++s) {
        const int buf = s & 1;
        __syncthreads();
        if (s + 1 < nsteps) STAGE((s + 1) * 64, buf ^ 1);

        f16x8 fa[2][2], fb[2][2];
#pragma unroll
        for (int ti = 0; ti < 2; ++ti)
#pragma unroll
            for (int kc = 0; kc < 2; ++kc) {
                fa[ti][kc] = *(const f16x8*)&sA[buf][KSWZ(wm + ti * 16 + fr,
                                                          kc * 32 + quad * 8)];
                fb[ti][kc] = *(const f16x8*)&sB[buf][KSWZ(wn + ti * 16 + fr,
                                                          kc * 32 + quad * 8)];
            }
#pragma unroll
        for (int ti = 0; ti < 2; ++ti)
#pragma unroll
            for (int tj = 0; tj < 2; ++tj)
#pragma unroll
                for (int kc = 0; kc < 2; ++kc)
                    acc[ti][tj] = __builtin_amdgcn_mfma_f32_16x16x32_f16(
                        fa[ti][kc], fb[tj][kc], acc[ti][tj], 0, 0, 0);
    }
#undef STAGE

    if (omode == 0) {
        float* Cf = (float*)C;
#pragma unroll
        for (int ti = 0; ti < 2; ++ti) {
            int rowb = m0 + wm + ti * 16 + quad * 4;
#pragma unroll
            for (int tj = 0; tj < 2; ++tj) {
                int col = n0 + wn + tj * 16 + fr;
                float bb = bias ? bias[col] : 0.f;
#pragma unroll
                for (int j2 = 0; j2 < 4; ++j2)
                    Cf[(size_t)(rowb + j2) * N + col] = acc[ti][tj][j2] + bb;
            }
        }
    } else {
        unsigned short* Cu = (unsigned short*)C;
        const bool vb = (omode == 1) && (n0 >= 1024);   // V region -> bf16
#pragma unroll
        for (int ti = 0; ti < 2; ++ti) {
            int rowb = m0 + wm + ti * 16 + quad * 4;
#pragma unroll
            for (int tj = 0; tj < 2; ++tj) {
                int col = n0 + wn + tj * 16 + fr;
#pragma unroll
                for (int j2 = 0; j2 < 4; ++j2) {
                    float v = acc[ti][tj][j2];
                    Cu[(size_t)(rowb + j2) * N + col] = vb ? f2bf(v) : f2h(v);
                }
            }
        }
    }
}

// ---------------------------------------------------------------------------
// drk[h][jj] = sum_d (rpb[h,d]-rcb[h,d]) * rk[jj, h*64+d]   (rk now f16)
// ---------------------------------------------------------------------------
__global__ __launch_bounds__(256) void drk_kernel(
    const _Float16* __restrict__ rkh, const float* __restrict__ cb,
    const float* __restrict__ rb, float* __restrict__ drk)
{
    int idx = blockIdx.x * 256 + threadIdx.x;
    if (idx >= 8 * RLEN) return;
    int jj = idx >> 3, h = idx & 7;
    const _Float16* rrow = rkh + (size_t)jj * RKLD + h * 64;
    float s0 = 0, s1 = 0, s2 = 0, s3 = 0;
#pragma unroll
    for (int d4 = 0; d4 < 16; ++d4) {
        f16x4 rv = *(const f16x4*)(rrow + d4 * 4);
        float dx = rb[h * 64 + d4 * 4 + 0] - cb[h * 64 + d4 * 4 + 0];
        float dy = rb[h * 64 + d4 * 4 + 1] - cb[h * 64 + d4 * 4 + 1];
        float dz = rb[h * 64 + d4 * 4 + 2] - cb[h * 64 + d4 * 4 + 2];
        float dw = rb[h * 64 + d4 * 4 + 3] - cb[h * 64 + d4 * 4 + 3];
        s0 = fmaf(dx, (float)rv[0], s0); s1 = fmaf(dy, (float)rv[1], s1);
        s2 = fmaf(dz, (float)rv[2], s2); s3 = fmaf(dw, (float)rv[3], s3);
    }
    drk[h * RLEN + jj] = (s0 + s1) + (s2 + s3);
}

// ---------------------------------------------------------------------------
// Banded rel logits via f16 MFMA; rk band staged DIRECT via global_load_lds
// (source pre-swizzled for KSWZ — zero staging VALU). Output SHIFTED+
// TRANSPOSED f16: relbT[bh][bi][jl][r], jl = ccg-127+r.
// ---------------------------------------------------------------------------
__global__ __launch_bounds__(256) void relb_mfma(
    const _Float16* __restrict__ qkvh, const _Float16* __restrict__ rkh,
    const float* __restrict__ rb, _Float16* __restrict__ relbT)
{
    __shared__ _Float16 sR[8192];   // 128 band rows x 64 d
    const int ct = blockIdx.x, bi = blockIdx.y, bh = blockIdx.z;
    const int b = bh >> 3, h = bh & 7;
    const int i0 = bi * 128;
    const int c0 = (bi == 0) ? 0 : (bi - 1) * 128;
    const int jjbase = c0 - i0 - 127 + (NSEQ - 1) + ct * 128;  // in [1280,1920)
    const int t = threadIdx.x;
    const int wave = t >> 6, lane = t & 63;
    const int fr = lane & 15, quad = lane >> 4;

    // ---- stage rk band: direct global->LDS, pre-swizzled source ----
    {
        const _Float16* Rg = rkh + (size_t)jjbase * RKLD + h * 64;
#pragma unroll
        for (int it = 0; it < 4; ++it) {
            int cidx = it * 256 + t;           // 0..1023 chunk id
            int row = cidx >> 3, slot = cidx & 7;
            int gch = slot ^ (row & 7);
            cp16(Rg + (size_t)row * RKLD + gch * 8,
                 &sR[it * 2048 + wave * 512]);
        }
    }
    // ---- Q + rel-pos-bias fragments (f16 source) ----
    f16x8 qf[2][2];
    {
        const _Float16* Qg = qkvh + ((size_t)(b * NSEQ + i0)) * HD3 + h * 64;
#pragma unroll
        for (int ti = 0; ti < 2; ++ti)
#pragma unroll
            for (int kc = 0; kc < 2; ++kc) {
                int m = wave * 32 + ti * 16 + fr;
                int k8 = kc * 32 + quad * 8;
                f16x8 qv = *(const f16x8*)(Qg + (size_t)m * HD3 + k8);
                const float* cp = rb + h * 64 + k8;
                _Float16 hx[8];
#pragma unroll
                for (int u = 0; u < 8; ++u)
                    hx[u] = (_Float16)((float)qv[u] + cp[u]);
                qf[ti][kc] = *(f16x8*)hx;
            }
    }
    __syncthreads();

    // ---- S = (Q+rpb) · rk^T ----
    f32x4 sacc[2][8];
#pragma unroll
    for (int i = 0; i < 2; ++i)
#pragma unroll
        for (int j = 0; j < 8; ++j)
#pragma unroll
            for (int c = 0; c < 4; ++c) sacc[i][j][c] = 0.f;

#pragma unroll
    for (int kc = 0; kc < 2; ++kc) {
        f16x8 bv[8];
#pragma unroll
        for (int tj = 0; tj < 8; ++tj)
            bv[tj] = *(const f16x8*)&sR[KSWZ(tj * 16 + fr, kc * 32 + quad * 8)];
#pragma unroll
        for (int ti = 0; ti < 2; ++ti)
#pragma unroll
            for (int tj = 0; tj < 8; ++tj)
                sacc[ti][tj] = __builtin_amdgcn_mfma_f32_16x16x32_f16(
                    qf[ti][kc], bv[tj], sacc[ti][tj], 0, 0, 0);
    }

    // ---- shifted scatter-store to relbT ----
    size_t bb_ = ((size_t)bh * NB + bi) * 512;
#pragma unroll
    for (int ti = 0; ti < 2; ++ti) {
        int mr = wave * 32 + ti * 16 + quad * 4;
#pragma unroll
        for (int tj = 0; tj < 8; ++tj) {
            int ccg = ct * 128 + tj * 16 + fr;
#pragma unroll
            for (int reg = 0; reg < 4; ++reg) {
                int r = mr + reg;
                int jl = ccg - 127 + r;            // < 512 always
                if (jl >= 0)
                    relbT[(bb_ + jl) * 128 + r] = (_Float16)sacc[ti][tj][reg];
            }
        }
    }
}

// ---------------------------------------------------------------------------
// MFMA flash attention (local window) + FUSED global-column contribution.
// qkv stored low-precision at the GEMM: Q,K f16 / V bf16. K staged DIRECT via
// global_load_lds (pre-swizzled source, zero VALU); V transpose is pure ushort
// moves. P bf16 (unnormalized softmax: p~1e13, f16 overflows — R3).
// ct==0 & bi>=2 blocks fold in the 4 global columns (p_g/vg/lg in LDS).
// ---------------------------------------------------------------------------
__global__ __launch_bounds__(256) void attn_mfma(
    const _Float16* __restrict__ qkvh, const _Float16* __restrict__ relbT,
    const _Float16* __restrict__ rkh, const float* __restrict__ drk,
    const float* __restrict__ cb, float* __restrict__ O_part,
    float* __restrict__ l_part)
{
    __shared__ unsigned short sKP[16384];   // K f16 [0:8192] -> P bf16 (PSWZ, full)
    __shared__ unsigned short sVt[64 * VSTR];  // V^T bf16 [d][VSTR]
    __shared__ float p_g[128 * 4];          // fused-gcols p per (row, j)
    __shared__ __align__(16) float vg[4 * 64];  // global V rows 0..3
    __shared__ float lg[128];               // fused-gcols l per row
    const int ct = blockIdx.x, bi = blockIdx.y, bh = blockIdx.z;
    const int b = bh >> 3, h = bh & 7;
    const int i0 = bi * 128;
    const int c0 = (bi == 0) ? 0 : (bi - 1) * 128;
    const int c1 = (bi == NB - 1) ? NSEQ : (bi + 2) * 128;
    const int ctile = c0 + ct * 128;
    const int t = threadIdx.x;
    const int wave = t >> 6, lane = t & 63;
    const int fr = lane & 15, quad = lane >> 4;

    float* Op = O_part + (((size_t)ct * 16 + bh) * NSEQ + i0) * 64;
    float* lp = l_part + ((size_t)ct * 16 + bh) * NSEQ + i0;

    if (ctile >= c1) {      // inactive edge tile: zero slice
        for (int k2 = t; k2 < 8192; k2 += 256) Op[k2] = 0.f;
        if (t < 128) lp[t] = 0.f;
        return;
    }

    const bool do_g = (ct == 0 && bi >= 2);
    const unsigned short* Vall = (const unsigned short*)qkvh;

    // ---- stage K: direct global->LDS, pre-swizzled source (f16 bits) ----
    {
        const _Float16* Kg = qkvh + ((size_t)(b * NSEQ + ctile)) * HD3 + 512 + h * 64;
#pragma unroll
        for (int it = 0; it < 4; ++it) {
            int cidx = it * 256 + t;           // 0..1023
            int row = cidx >> 3, slot = cidx & 7;
            int gch = slot ^ (row & 7);
            cp16(Kg + (size_t)row * HD3 + gch * 8,
                 (unsigned short*)&sKP[it * 2048 + wave * 512]);
        }
    }
    // ---- stage V transposed (bf16 bits, pure moves, [d][VSTR]) ----
    {
        const unsigned short* Vg = Vall + ((size_t)(b * NSEQ + ctile)) * HD3
                                   + 1024 + h * 64;
#pragma unroll
        for (int it = 0; it < 2; ++it) {
            int lin = it * 256 + t;            // 0..511
            int r4 = (lin >> 4) * 4, d4 = (lin & 15) * 4;
            ushort4 v0 = *(const ushort4*)(Vg + (size_t)(r4 + 0) * HD3 + d4);
            ushort4 v1 = *(const ushort4*)(Vg + (size_t)(r4 + 1) * HD3 + d4);
            ushort4 v2 = *(const ushort4*)(Vg + (size_t)(r4 + 2) * HD3 + d4);
            ushort4 v3 = *(const ushort4*)(Vg + (size_t)(r4 + 3) * HD3 + d4);
            const unsigned short* p0 = (const unsigned short*)&v0;
            const unsigned short* p1 = (const unsigned short*)&v1;
            const unsigned short* p2 = (const unsigned short*)&v2;
            const unsigned short* p3 = (const unsigned short*)&v3;
#pragma unroll
            for (int dd = 0; dd < 4; ++dd) {
                ushort4 hh;
                hh.x = p0[dd]; hh.y = p1[dd]; hh.z = p2[dd]; hh.w = p3[dd];
                *(ushort4*)&sVt[(d4 + dd) * VSTR + r4] = hh;
            }
        }
    }
    // ---- fused global-column (cols 0..3) contribution ----
    if (do_g) {
        if (t < 128) {
            const int r = t;
            const int i = i0 + r;
            const int jjb = NSEQ - 1 - i;       // jj for j=0; j adds +j
            const _Float16* qrow = qkvh + (size_t)(b * NSEQ + i) * HD3 + h * 64;
            const _Float16* krow = qkvh + (size_t)(b * NSEQ) * HD3 + 512 + h * 64;
            const _Float16* rrow = rkh + (size_t)jjb * RKLD + h * 64;
            float s[4] = {0.f, 0.f, 0.f, 0.f};
#pragma unroll
            for (int d4 = 0; d4 < 16; ++d4) {
                f16x4 qv = *(const f16x4*)(qrow + d4 * 4);
                float4 cv = *(const float4*)(cb + h * 64 + d4 * 4);
                float q0 = (float)qv[0] + cv.x, q1 = (float)qv[1] + cv.y;
                float q2 = (float)qv[2] + cv.z, q3 = (float)qv[3] + cv.w;
#pragma unroll
                for (int j = 0; j < 4; ++j) {
                    f16x4 kv = *(const f16x4*)(krow + (size_t)j * HD3 + d4 * 4);
                    f16x4 rv = *(const f16x4*)(rrow + (size_t)j * RKLD + d4 * 4);
                    s[j] = fmaf(q0, (float)kv[0] + (float)rv[0], s[j]);
                    s[j] = fmaf(q1, (float)kv[1] + (float)rv[1], s[j]);
                    s[j] = fmaf(q2, (float)kv[2] + (float)rv[2], s[j]);
                    s[j] = fmaf(q3, (float)kv[3] + (float)rv[3], s[j]);
                }
            }
            float l = 0.f;
#pragma unroll
            for (int j = 0; j < 4; ++j) {
                float p = __expf(s[j] + drk[h * RLEN + jjb + j]);
                p_g[r * 4 + j] = p;
                l += p;
            }
            lg[r] = l;
        } else {
            const unsigned short* Vg0 = Vall + (size_t)(b * NSEQ) * HD3
                                        + 1024 + h * 64;
            int u = (t - 128) * 2;
#pragma unroll
            for (int w = 0; w < 2; ++w) {
                int idx = u + w;               // j*64 + d
                vg[idx] = bf2f(Vg0[(size_t)(idx >> 6) * HD3 + (idx & 63)]);
            }
        }
    }
    // ---- Q fragments in registers (f16 q + content bias) ----
    f16x8 qf[2][2];
    {
        const _Float16* Qg = qkvh + ((size_t)(b * NSEQ + i0)) * HD3 + h * 64;
#pragma unroll
        for (int ti = 0; ti < 2; ++ti)
#pragma unroll
            for (int kc = 0; kc < 2; ++kc) {
                int m = wave * 32 + ti * 16 + fr;
                int k8 = kc * 32 + quad * 8;
                f16x8 qv = *(const f16x8*)(Qg + (size_t)m * HD3 + k8);
                const float* cp = cb + h * 64 + k8;
                _Float16 hx[8];
#pragma unroll
                for (int u = 0; u < 8; ++u)
                    hx[u] = (_Float16)((float)qv[u] + cp[u]);
                qf[ti][kc] = *(f16x8*)hx;
            }
    }
    __syncthreads();

    // ---- S = Q K^T (f16 MFMA, f32 accum) ----
    f32x4 sacc[2][8];
#pragma unroll
    for (int i = 0; i < 2; ++i)
#pragma unroll
        for (int j = 0; j < 8; ++j)
#pragma unroll
            for (int c = 0; c < 4; ++c) sacc[i][j][c] = 0.f;

#pragma unroll
    for (int kc = 0; kc < 2; ++kc) {
        f16x8 bv[8];
#pragma unroll
        for (int tj = 0; tj < 8; ++tj)
            bv[tj] = *(const f16x8*)&sKP[KSWZ(tj * 16 + fr, kc * 32 + quad * 8)];
#pragma unroll
        for (int ti = 0; ti < 2; ++ti)
#pragma unroll
            for (int tj = 0; tj < 8; ++tj)
                sacc[ti][tj] = __builtin_amdgcn_mfma_f32_16x16x32_f16(
                    qf[ti][kc], bv[tj], sacc[ti][tj], 0, 0, 0);
    }
    __syncthreads();   // all waves done reading K before P overwrites it

    // ---- rel + exp -> P (bf16, swizzled [r][j]); row-sums ----
    const _Float16* relbase = relbT + (((size_t)bh * NB + bi) * 512 + ct * 128) * 128;
    float lsum[2][4] = {{0.f, 0.f, 0.f, 0.f}, {0.f, 0.f, 0.f, 0.f}};
#pragma unroll
    for (int ti = 0; ti < 2; ++ti) {
        int mr = wave * 32 + ti * 16 + quad * 4;
#pragma unroll
        for (int tj = 0; tj < 8; ++tj) {
            int j = tj * 16 + fr;
            f16x4 rl = *(const f16x4*)&relbase[(size_t)j * 128 + mr];
#pragma unroll
            for (int reg = 0; reg < 4; ++reg) {
                int r = mr + reg;
                float p = __expf(sacc[ti][tj][reg] + (float)rl[reg]);
                unsigned short pb = f2bf(p);
                lsum[ti][reg] += bf2f(pb);     // l consistent with bf16 P
                sKP[PSWZ(r, j)] = pb;
            }
        }
    }
#pragma unroll
    for (int m2 = 1; m2 < 16; m2 <<= 1)
#pragma unroll
        for (int ti = 0; ti < 2; ++ti)
#pragma unroll
            for (int reg = 0; reg < 4; ++reg)
                lsum[ti][reg] += __shfl_xor(lsum[ti][reg], m2, 64);
    if (fr == 0) {
#pragma unroll
        for (int ti = 0; ti < 2; ++ti) {
            int mr = wave * 32 + ti * 16 + quad * 4;
#pragma unroll
            for (int reg = 0; reg < 4; ++reg)
                lp[mr + reg] = lsum[ti][reg] + (do_g ? lg[mr + reg] : 0.f);
        }
    }

    // ---- O^T = Vt x P^T (bf16 MFMA; each wave consumes only its own P rows) ----
    f32x4 oacc[4][2];
#pragma unroll
    for (int i = 0; i < 4; ++i)
#pragma unroll
        for (int j = 0; j < 2; ++j)
#pragma unroll
            for (int c = 0; c < 4; ++c) oacc[i][j][c] = 0.f;

#pragma unroll
    for (int kc = 0; kc < 4; ++kc) {
        bf16x8 pbv[2];
#pragma unroll
        for (int rt2 = 0; rt2 < 2; ++rt2) {
            int r = (wave * 2 + rt2) * 16 + fr;
            pbv[rt2] = *(const bf16x8*)&sKP[PSWZ(r, kc * 32 + quad * 8)];
        }
#pragma unroll
        for (int dt = 0; dt < 4; ++dt) {
            bf16x8 av = *(const bf16x8*)&sVt[(dt * 16 + fr) * VSTR + kc * 32 + quad * 8];
#pragma unroll
            for (int rt2 = 0; rt2 < 2; ++rt2)
                oacc[dt][rt2] = __builtin_amdgcn_mfma_f32_16x16x32_bf16(
                    av, pbv[rt2], oacc[dt][rt2], 0, 0, 0);
        }
    }
#pragma unroll
    for (int rt2 = 0; rt2 < 2; ++rt2) {
        int r = (wave * 2 + rt2) * 16 + fr;
        float pg0 = 0.f, pg1 = 0.f, pg2 = 0.f, pg3 = 0.f;
        if (do_g) {
            pg0 = p_g[r * 4 + 0]; pg1 = p_g[r * 4 + 1];
            pg2 = p_g[r * 4 + 2]; pg3 = p_g[r * 4 + 3];
        }
#pragma unroll
        for (int dt = 0; dt < 4; ++dt) {
            int d = dt * 16 + quad * 4;
            float4 ov = make_float4(oacc[dt][rt2][0], oacc[dt][rt2][1],
                                    oacc[dt][rt2][2], oacc[dt][rt2][3]);
            if (do_g) {
                float4 v0 = *(const float4*)&vg[0 * 64 + d];
                float4 v1 = *(const float4*)&vg[1 * 64 + d];
                float4 v2 = *(const float4*)&vg[2 * 64 + d];
                float4 v3 = *(const float4*)&vg[3 * 64 + d];
                ov.x += pg0 * v0.x + pg1 * v1.x + pg2 * v2.x + pg3 * v3.x;
                ov.y += pg0 * v0.y + pg1 * v1.y + pg2 * v2.y + pg3 * v3.y;
                ov.z += pg0 * v0.z + pg1 * v1.z + pg2 * v2.z + pg3 * v3.z;
                ov.w += pg0 * v0.w + pg1 * v1.w + pg2 * v2.w + pg3 * v3.w;
            }
            *(float4*)(Op + (size_t)r * 64 + d) = ov;
        }
    }
}

// ---------------------------------------------------------------------------
// Global-ROW attention partials: grid (12 col-chunks, 64 bhi), 256 thr.
// Reads f16 Q/K, f16 rel_k, bf16 V.
// ---------------------------------------------------------------------------
__global__ __launch_bounds__(256) void grows_part(
    const _Float16* __restrict__ qkvh, const _Float16* __restrict__ rkh,
    const float* __restrict__ drk, const float* __restrict__ cb,
    float* __restrict__ g_O, float* __restrict__ g_l)
{
    __shared__ float qc_s[64];
    __shared__ float p_s[128];
    __shared__ float obuf[4][64];
    __shared__ float lred[2];
    const int chunk = blockIdx.x;        // 0..11
    const int bhi = blockIdx.y;          // 0..63
    const int i = bhi & 3, h = (bhi >> 2) & 7, b = bhi >> 5;
    const int t = threadIdx.x;
    const int c0 = chunk * 128;
    if (t < 64)
        qc_s[t] = (float)qkvh[(size_t)(b * NSEQ + i) * HD3 + h * 64 + t]
                  + cb[h * 64 + t];
    __syncthreads();
    if (t < 128) {
        int j = c0 + t;
        const _Float16* krow = qkvh + (size_t)(b * NSEQ + j) * HD3 + 512 + h * 64;
        int jj = j - i + (NSEQ - 1);
        const _Float16* rrow = rkh + (size_t)jj * RKLD + h * 64;
        float s0 = 0, s1 = 0, s2 = 0, s3 = 0;
#pragma unroll
        for (int d4 = 0; d4 < 16; ++d4) {
            f16x4 kv = *(const f16x4*)(krow + d4 * 4);
            f16x4 rv = *(const f16x4*)(rrow + d4 * 4);
            float4 qv = *(const float4*)(&qc_s[d4 * 4]);
            s0 = fmaf(qv.x, (float)kv[0] + (float)rv[0], s0);
            s1 = fmaf(qv.y, (float)kv[1] + (float)rv[1], s1);
            s2 = fmaf(qv.z, (float)kv[2] + (float)rv[2], s2);
            s3 = fmaf(qv.w, (float)kv[3] + (float)rv[3], s3);
        }
        float p = __expf((s0 + s1) + (s2 + s3) + drk[h * RLEN + jj]);
        p_s[t] = p;
        float ls = p;
#pragma unroll
        for (int off = 32; off > 0; off >>= 1)
            ls += __shfl_down(ls, off, 64);
        if ((t & 63) == 0) lred[t >> 6] = ls;
    }
    __syncthreads();
    {
        const int d = t & 63, g = t >> 6;
        float a0 = 0, a1 = 0;
        const unsigned short* vbase = (const unsigned short*)qkvh
            + (size_t)(b * NSEQ + c0 + g * 32) * HD3 + 1024 + h * 64 + d;
#pragma unroll
        for (int j2 = 0; j2 < 32; j2 += 2) {
            a0 = fmaf(p_s[g * 32 + j2],     bf2f(vbase[(size_t)j2 * HD3]),       a0);
            a1 = fmaf(p_s[g * 32 + j2 + 1], bf2f(vbase[(size_t)(j2 + 1) * HD3]), a1);
        }
        obuf[g][d] = a0 + a1;
    }
    __syncthreads();
    if (t < 64) {
        float o = (obuf[0][t] + obuf[1][t]) + (obuf[2][t] + obuf[3][t]);
        g_O[((size_t)chunk * 64 + bhi) * 64 + t] = o;
        if (t == 0) g_l[chunk * 64 + bhi] = lred[0] + lred[1];
    }
}

// ---------------------------------------------------------------------------
// Merge 3 ct-slices, normalize, emit ao as f16 (single-term out-proj).
// Rows i<4 (global rows) take their (O,l) from the 12 grows_part chunks.
// ---------------------------------------------------------------------------
__global__ __launch_bounds__(256) void norm_merge(
    const float* __restrict__ O_part, const float* __restrict__ l_part,
    const float* __restrict__ g_O, const float* __restrict__ g_l,
    _Float16* __restrict__ aoh)
{
    const int bh = blockIdx.y, b = bh >> 3, h = bh & 7;
    const int i = blockIdx.x * 16 + (threadIdx.x >> 4);
    const int d4 = threadIdx.x & 15;
    float ox = 0, oy = 0, oz = 0, ow = 0, l = 0;
    if (i < 4) {          // global row: sum the 12 column-chunk partials
        const int bhi = bh * 4 + i;
#pragma unroll
        for (int c = 0; c < 12; ++c) {
            const float* gp = g_O + ((size_t)c * 64 + bhi) * 64 + d4 * 4;
            ox += gp[0]; oy += gp[1]; oz += gp[2]; ow += gp[3];
            l += g_l[c * 64 + bhi];
        }
    } else {
#pragma unroll
        for (int s = 0; s < 3; ++s) {
            const float* Opp = O_part + (((size_t)s * 16 + bh) * NSEQ + i) * 64 + d4 * 4;
            float4 p = *(const float4*)Opp;
            ox += p.x; oy += p.y; oz += p.z; ow += p.w;
            l += l_part[((size_t)s * 16 + bh) * NSEQ + i];
        }
    }
    float inv = 1.f / l;
    union { _Float16 h[4]; ushort4 u; } cc;
    cc.h[0] = (_Float16)(ox * inv); cc.h[1] = (_Float16)(oy * inv);
    cc.h[2] = (_Float16)(oz * inv); cc.h[3] = (_Float16)(ow * inv);
    size_t o = ((size_t)(b * NSEQ + i)) * 512 + h * 64 + d4 * 4;
    *(ushort4*)(aoh + o) = cc.u;
}

// ---------------------------------------------------------------------------
extern "C" void kernel_launch(void* const* d_in, const int* in_sizes, int n_in,
                              void* d_out, int out_size, void* d_ws, size_t ws_size,
                              hipStream_t stream)
{
    const float* x    = (const float*)d_in[0];
    const float* Wq   = (const float*)d_in[1];
    const float* Wk   = (const float*)d_in[2];
    const float* Wv   = (const float*)d_in[3];
    const float* Wrel = (const float*)d_in[4];
    const float* cb   = (const float*)d_in[5];
    const float* rb   = (const float*)d_in[6];
    const float* Wo   = (const float*)d_in[7];
    const float* bo   = (const float*)d_in[8];
    const float* pe   = (const float*)d_in[9];
    float* out = (float*)d_out;

    float* ws = (float*)d_ws;
    _Float16* qkvh = (_Float16*)ws;                      // [3072][1536] Q,K f16 | V bf16
    _Float16* rkh  = (_Float16*)(ws + 2359296);          // [3072][512] f16 (row 3071 scratch)
    float* drk   = ws + 3145728;                         // [8][3071] f32
    _Float16* aoh = (_Float16*)(ws + 3170304);           // [3072][512] f16
    _Float16* woh = (_Float16*)(ws + 3956736);           // WoT [1536][512] f16
    float* R = ws + 4349952;                             // aliased region
    _Float16* relbT = (_Float16*)R;                          // [16][12][512][128] f16
    _Float16* xh  = (_Float16*)R;                            // dead before relbT written
    _Float16* wqh = (_Float16*)(R + 2359296);                // WqkvT [1536][1536] f16
    float* g_O = R + 6291456;                            // [12][64][64] f32 (after relbT)
    float* g_l = R + 6340608;                            // [12][64] f32
    float* O_part = ws + 10691328;                       // [3][16][1536][64] f32
    float* l_part = ws + 15409920;                       // [3][16][1536] f32
    _Float16* peh   = (_Float16*)(ws + 15483648);        // [3072][192] f16 (row 3071 scratch)
    _Float16* wrelT = (_Float16*)(ws + 15778560);        // WrelT [512][192] f16

    dim3 blk(256);
    split2_f16<<<5184, blk, 0, stream>>>(x, xh, pe, peh);
    wsplit_all<<<dim3(8, 24, 5), blk, 0, stream>>>(Wq, Wk, Wv, Wo, Wrel,
                                                   wqh, woh, wrelT);
    gemm_f16k<<<dim3(24, 48), blk, 0, stream>>>(xh, wqh, nullptr, qkvh,
                                                3072, 1536, 1536, 1);
    gemm_f16k<<<dim3(8, 48), blk, 0, stream>>>(peh, wrelT, nullptr, rkh,
                                               3072, 512, 192, 2);
    drk_kernel<<<96, blk, 0, stream>>>(rkh, cb, rb, drk);
    relb_mfma<<<dim3(4, 12, 16), blk, 0, stream>>>(qkvh, rkh, rb, relbT);
    attn_mfma<<<dim3(3, 12, 16), blk, 0, stream>>>(qkvh, relbT, rkh, drk, cb,
                                                   O_part, l_part);
    grows_part<<<dim3(12, 64), blk, 0, stream>>>(qkvh, rkh, drk, cb, g_O, g_l);
    norm_merge<<<dim3(96, 16), blk, 0, stream>>>(O_part, l_part, g_O, g_l, aoh);
    gemm_f16k<<<dim3(24, 48), blk, 0, stream>>>(aoh, woh, bo, out,
                                                3072, 1536, 512, 0);
}